// Round 7
// baseline (825.687 us; speedup 1.0000x reference)
//
#include <hip/hip_runtime.h>
#include <hip/hip_bf16.h>

typedef __bf16 bf16x8 __attribute__((ext_vector_type(8)));
typedef __bf16 bf16x4 __attribute__((ext_vector_type(4)));
typedef float f32x4 __attribute__((ext_vector_type(4)));

#define B_N 1024
#define D_N 256
#define A_N 6
#define M_N 200000
#define K_N 16
#define H1_N 128
#define H2_N 64
#define NTILES 3125     // 200000 / 64
#define S_TILES 6       // prepass tiles per chunk
#define S_CHUNKS 32     // prepass chunks -> sample = 32*6*64 = 12288 rows
#define F_NC 128        // filter: m-chunk count (grid.x)
#define F_BY 4          // filter: b-groups of 256 cols (grid.y)
#define CAP 1024        // per-b survivor capacity
#define MEMCVT_BLKS (M_N / 4)

__device__ __forceinline__ float wred_sum(float v) {
#pragma unroll
  for (int o = 1; o < 64; o <<= 1) v += __shfl_xor(v, o, 64);
  return v;
}

// descending top-16 insert; compile-time indices only (stays in VGPRs)
__device__ __forceinline__ void topk_insert(float (&lst)[16], float v) {
  if (v <= lst[15]) return;
#pragma unroll
  for (int i = 0; i < 16; ++i) {
    bool gt = v > lst[i];
    float hi = gt ? v : lst[i];
    v = gt ? lst[i] : v;
    lst[i] = hi;
  }
}

__device__ __forceinline__ void load_lds16(const void* g, void* l) {
  __builtin_amdgcn_global_load_lds(
      (const __attribute__((address_space(1))) unsigned int*)g,
      (__attribute__((address_space(3))) unsigned int*)l, 16, 0, 0);
}

// ---------- fused: memcvt (blocks 0..49999) + forward model (blocks 50000+) -
__global__ __launch_bounds__(256) void prep_kernel(
    const float* __restrict__ mem, __bf16* __restrict__ memn,
    const float* __restrict__ z_t, const float* __restrict__ action,
    const float* __restrict__ z_t1, const float* __restrict__ sigma,
    const float* __restrict__ W1, const float* __restrict__ b1,
    const float* __restrict__ g1, const float* __restrict__ be1,
    const float* __restrict__ W2, const float* __restrict__ b2,
    const float* __restrict__ g2, const float* __restrict__ be2,
    const float* __restrict__ W3, const float* __restrict__ b3,
    float* __restrict__ out, __bf16* __restrict__ z_n) {
  __shared__ float s_inp[D_N + A_N];
  __shared__ float s_h1[H1_N];
  __shared__ float s_h2[H2_N];
  __shared__ float red[8];
  const int t = threadIdx.x;
  const int w = t >> 6;

  if (blockIdx.x < MEMCVT_BLKS) {
    const int l = t & 63;
    const size_t row = (size_t)blockIdx.x * 4 + w;
    const float4 v = ((const float4*)(mem + row * D_N))[l];
    float ss = wred_sum(v.x * v.x + v.y * v.y + v.z * v.z + v.w * v.w);
    const float inv = 1.0f / (sqrtf(ss) + 1e-8f);
    bf16x4 p;
    p[0] = (__bf16)(v.x * inv); p[1] = (__bf16)(v.y * inv);
    p[2] = (__bf16)(v.z * inv); p[3] = (__bf16)(v.w * inv);
    *(bf16x4*)(memn + row * D_N + l * 4) = p;
    return;
  }

  const int b = blockIdx.x - MEMCVT_BLKS;

  float zv = z_t[b * D_N + t];
  s_inp[t] = zv;
  if (t < A_N) s_inp[D_N + t] = action[b * A_N + t];

  float ss = wred_sum(zv * zv);
  if ((t & 63) == 0) red[w] = ss;
  __syncthreads();
  float tot = red[0] + red[1] + red[2] + red[3];
  float invz = 1.0f / (sqrtf(tot) + 1e-8f);
  z_n[b * D_N + t] = (__bf16)(zv * invz);

  float y1 = 0.0f;
  if (t < H1_N) {
    y1 = b1[t];
    for (int k = 0; k < D_N + A_N; ++k) y1 += s_inp[k] * W1[k * H1_N + t];
  }
  __syncthreads();
  float s1 = wred_sum(t < H1_N ? y1 : 0.0f);
  float q1 = wred_sum(t < H1_N ? y1 * y1 : 0.0f);
  if ((t & 63) == 0) { red[w] = s1; red[4 + w] = q1; }
  __syncthreads();
  float S1 = red[0] + red[1] + red[2] + red[3];
  float Q1 = red[4] + red[5] + red[6] + red[7];
  float mu1 = S1 / (float)H1_N;
  float var1 = Q1 / (float)H1_N - mu1 * mu1;
  float rs1 = rsqrtf(var1 + 1e-5f);
  if (t < H1_N) {
    float xn = (y1 - mu1) * rs1;
    s_h1[t] = fmaxf(0.0f, xn * g1[t] + be1[t]);
  }
  __syncthreads();

  float y2 = 0.0f;
  if (t < H2_N) {
    y2 = b2[t];
    for (int k = 0; k < H1_N; ++k) y2 += s_h1[k] * W2[k * H2_N + t];
  }
  __syncthreads();
  float s2 = wred_sum(t < H2_N ? y2 : 0.0f);
  float q2 = wred_sum(t < H2_N ? y2 * y2 : 0.0f);
  if ((t & 63) == 0) { red[w] = s2; red[4 + w] = q2; }
  __syncthreads();
  float S2 = red[0] + red[1] + red[2] + red[3];
  float Q2 = red[4] + red[5] + red[6] + red[7];
  float mu2 = S2 / (float)H2_N;
  float var2 = Q2 / (float)H2_N - mu2 * mu2;
  float rs2 = rsqrtf(var2 + 1e-5f);
  if (t < H2_N) {
    float xn = (y2 - mu2) * rs2;
    s_h2[t] = fmaxf(0.0f, xn * g2[t] + be2[t]);
  }
  __syncthreads();

  float zp = b3[t];
  for (int k = 0; k < H2_N; ++k) zp += s_h2[k] * W3[k * D_N + t];
  float d = zp - z_t1[b * D_N + t];
  __syncthreads();
  float pe = wred_sum(d * d);
  if ((t & 63) == 0) red[w] = pe;
  __syncthreads();
  if (t == 0) {
    float PE = (red[0] + red[1] + red[2] + red[3]) / (float)D_N;
    out[B_N + b] = PE;
    float s6 = 0.0f;
    for (int i = 0; i < A_N; ++i) s6 += sigma[b * A_N + i];
    out[2 * B_N + b] = s6 / (float)A_N;
  }
}

// ---------------- prepass: exact top-16 over 12288-row sample ---------------
__global__ __launch_bounds__(512) void prepass_kernel(
    const __bf16* __restrict__ memn, const __bf16* __restrict__ z_n,
    float* __restrict__ tcand) {
  __shared__ __bf16 tile[64 * 256];
  const int t = threadIdx.x;
  const int w = t >> 6;
  const int l = t & 63;
  const int c = l & 15;
  const int lg = l >> 4;
  const int brow = blockIdx.y * 128 + w * 16 + c;

  bf16x8 zf[8];
#pragma unroll
  for (int kc = 0; kc < 8; ++kc)
    zf[kc] = *(const bf16x8*)(z_n + brow * D_N + kc * 32 + lg * 8);

  float lst[16];
#pragma unroll
  for (int i = 0; i < 16; ++i) lst[i] = -3.0e38f;

  const int sr = t >> 3;
  const int sc = t & 7;
  char* tileb = (char*)tile;

  for (int tl = 0; tl < S_TILES; ++tl) {
    const int m0 = (blockIdx.x * S_TILES + tl) * 64;
#pragma unroll
    for (int i = 0; i < 4; ++i) {
      bf16x8 d = *(const bf16x8*)(memn + (size_t)(m0 + sr) * D_N + sc * 32 + i * 8);
      *(bf16x8*)(tileb + sr * 512 + ((sc * 64 + i * 16) ^ ((sr & 7) << 4))) = d;
    }
    __syncthreads();
#pragma unroll
    for (int mf = 0; mf < 4; ++mf) {
      const int row = mf * 16 + c;
      const int rsw = (row & 7) << 4;
      f32x4 acc = {0.f, 0.f, 0.f, 0.f};
#pragma unroll
      for (int kc = 0; kc < 8; ++kc) {
        const int inner = (kc * 64 + lg * 16) ^ rsw;
        bf16x8 a = *(const bf16x8*)(tileb + row * 512 + inner);
        acc = __builtin_amdgcn_mfma_f32_16x16x32_bf16(a, zf[kc], acc, 0, 0, 0);
      }
      topk_insert(lst, acc[0]);
      topk_insert(lst, acc[1]);
      topk_insert(lst, acc[2]);
      topk_insert(lst, acc[3]);
    }
    __syncthreads();
  }

  float mg[16];
#pragma unroll
  for (int r = 0; r < 16; ++r) {
    float h = lst[0];
    float g = fmaxf(h, __shfl_xor(h, 16, 64));
    g = fmaxf(g, __shfl_xor(g, 32, 64));
    unsigned long long bal = __ballot(h == g);
    unsigned long long grp = (bal >> c) & 0x0001000100010001ULL;
    int fs = __ffsll(grp) - 1;
    if ((lg << 4) == fs) {
#pragma unroll
      for (int i = 0; i < 15; ++i) lst[i] = lst[i + 1];
      lst[15] = -3.0e38f;
    }
    mg[r] = g;
  }
  if (l < 16) {
    float* dst = tcand + ((size_t)brow * S_CHUNKS + blockIdx.x) * 16;
#pragma unroll
    for (int i = 0; i < 16; i += 4) {
      float4 o = make_float4(mg[i], mg[i + 1], mg[i + 2], mg[i + 3]);
      *(float4*)(dst + i) = o;
    }
  }
}

// -------- tau: 16th-largest of the sample candidates (+ zero cnt) -----------
__global__ __launch_bounds__(64) void tau_kernel(
    const float* __restrict__ tcand, float* __restrict__ tau,
    int* __restrict__ cnt) {
  const int b = blockIdx.x;
  const int l = threadIdx.x;
  if (l == 0) cnt[b] = 0;
  float lst[16];
#pragma unroll
  for (int i = 0; i < 16; ++i) lst[i] = -3.0e38f;
  const float* cb = tcand + (size_t)b * (S_CHUNKS * 16);
#pragma unroll
  for (int k = 0; k < (S_CHUNKS * 16) / 64; ++k) topk_insert(lst, cb[k * 64 + l]);

  float g16 = -3.0e38f;
#pragma unroll
  for (int r = 0; r < K_N; ++r) {
    float h = lst[0];
    float g = h;
#pragma unroll
    for (int o = 1; o < 64; o <<= 1) g = fmaxf(g, __shfl_xor(g, o, 64));
    unsigned long long bal = __ballot(h == g);
    int winner = __ffsll(bal) - 1;
    if (l == winner) {
#pragma unroll
      for (int i = 0; i < 15; ++i) lst[i] = lst[i + 1];
      lst[15] = -3.0e38f;
    }
    g16 = g;
  }
  if (l == 0) tau[b] = g16;
}

// ---------------- filter (REAL, R6 structure): GEMM + threshold stash -------
__global__ __launch_bounds__(256, 2) void filter_kernel(
    const __bf16* __restrict__ memn, const __bf16* __restrict__ z_n,
    const float* __restrict__ tau, int* __restrict__ cnt,
    float* __restrict__ candv) {
  __shared__ __bf16 tile[2][64 * 256];  // 2 x 32 KB, fragment-contiguous
  const int t = threadIdx.x;
  const int w = t >> 6;
  const int l = t & 63;
  const int c = l & 15;
  const int lg = l >> 4;
  const int bx = blockIdx.x;
  const int bbase = blockIdx.y * 256 + w * 64 + c;

  f32x4 zr[4][8];
#pragma unroll
  for (int s = 0; s < 4; ++s)
#pragma unroll
    for (int kc = 0; kc < 8; ++kc)
      zr[s][kc] = *(const f32x4*)(z_n + (size_t)(bbase + s * 16) * D_N +
                                  kc * 32 + lg * 8);
#pragma unroll
  for (int s = 0; s < 4; ++s)
#pragma unroll
    for (int kc = 0; kc < 8; ++kc) asm volatile("" : "+v"(zr[s][kc]));

  float tauv[4];
#pragma unroll
  for (int s = 0; s < 4; ++s) tauv[s] = tau[bbase + s * 16];

  float st0[4], st1[4];
  int nss[4];
#pragma unroll
  for (int s = 0; s < 4; ++s) { st0[s] = 0.f; st1[s] = 0.f; nss[s] = 0; }

  char* tileb = (char*)tile;
#define STAGE(buf, tl_)                                                       \
  {                                                                           \
    const __bf16* _g = memn + (size_t)((tl_) * 64 + w * 16 + c) * D_N + lg * 8; \
    char* _d = tileb + (buf) * 32768 + w * 8192;                              \
    _Pragma("unroll") for (int i = 0; i < 8; ++i)                             \
        load_lds16(_g + i * 32, _d + i * 1024);                               \
  }

  int cur = 0;
  STAGE(0, bx)
  STAGE(1, bx + F_NC)

  for (int tl = bx; tl < NTILES; tl += F_NC) {
    asm volatile("s_waitcnt vmcnt(8)" ::: "memory");
    __builtin_amdgcn_s_barrier();
    __builtin_amdgcn_sched_barrier(0);
    const char* curb = tileb + cur * 32768;
#pragma unroll
    for (int mf = 0; mf < 4; ++mf) {
      f32x4 acc0 = {0.f, 0.f, 0.f, 0.f};
      f32x4 acc1 = {0.f, 0.f, 0.f, 0.f};
      f32x4 acc2 = {0.f, 0.f, 0.f, 0.f};
      f32x4 acc3 = {0.f, 0.f, 0.f, 0.f};
#pragma unroll
      for (int kc = 0; kc < 8; ++kc) {
        bf16x8 a = *(const bf16x8*)(curb + (mf * 8 + kc) * 1024 + l * 16);
        acc0 = __builtin_amdgcn_mfma_f32_16x16x32_bf16(
            a, __builtin_bit_cast(bf16x8, zr[0][kc]), acc0, 0, 0, 0);
        acc1 = __builtin_amdgcn_mfma_f32_16x16x32_bf16(
            a, __builtin_bit_cast(bf16x8, zr[1][kc]), acc1, 0, 0, 0);
        acc2 = __builtin_amdgcn_mfma_f32_16x16x32_bf16(
            a, __builtin_bit_cast(bf16x8, zr[2][kc]), acc2, 0, 0, 0);
        acc3 = __builtin_amdgcn_mfma_f32_16x16x32_bf16(
            a, __builtin_bit_cast(bf16x8, zr[3][kc]), acc3, 0, 0, 0);
      }
#define STASH(accv, s)                                                        \
      _Pragma("unroll") for (int j = 0; j < 4; ++j) {                         \
        float v = (accv)[j];                                                  \
        if (v >= tauv[s]) {                                                   \
          if (nss[s] == 0) { st0[s] = v; nss[s] = 1; }                        \
          else if (nss[s] == 1) { st1[s] = v; nss[s] = 2; }                   \
          else {                                                              \
            int p = atomicAdd(&cnt[bbase + (s) * 16], 1);                     \
            if (p < CAP) candv[(size_t)(bbase + (s) * 16) * CAP + p] = v;     \
          }                                                                   \
        }                                                                     \
      }
      STASH(acc0, 0) STASH(acc1, 1) STASH(acc2, 2) STASH(acc3, 3)
#undef STASH
    }
    asm volatile("s_waitcnt lgkmcnt(0)" ::: "memory");
    __builtin_amdgcn_s_barrier();
    int nx = tl + 2 * F_NC;
    if (nx >= NTILES) nx = bx;
    STAGE(cur, nx)
    cur ^= 1;
  }
#undef STAGE

#pragma unroll
  for (int s = 0; s < 4; ++s) {
    if (nss[s] > 0) {
      const int bb = bbase + s * 16;
      int p = atomicAdd(&cnt[bb], nss[s]);
      if (p < CAP) candv[(size_t)bb * CAP + p] = st0[s];
      if (nss[s] == 2 && p + 1 < CAP) candv[(size_t)bb * CAP + p + 1] = st1[s];
    }
  }
}

// ---------------- DIAG ablA: staging + barriers only ------------------------
__global__ __launch_bounds__(256, 2) void filter_ablA_kernel(
    const __bf16* __restrict__ memn) {
  __shared__ __bf16 tile[2][64 * 256];
  const int t = threadIdx.x;
  const int w = t >> 6;
  const int l = t & 63;
  const int c = l & 15;
  const int lg = l >> 4;
  const int bx = blockIdx.x;
  char* tileb = (char*)tile;
#define STAGE(buf, tl_)                                                       \
  {                                                                           \
    const __bf16* _g = memn + (size_t)((tl_) * 64 + w * 16 + c) * D_N + lg * 8; \
    char* _d = tileb + (buf) * 32768 + w * 8192;                              \
    _Pragma("unroll") for (int i = 0; i < 8; ++i)                             \
        load_lds16(_g + i * 32, _d + i * 1024);                               \
  }
  int cur = 0;
  STAGE(0, bx)
  STAGE(1, bx + F_NC)
  for (int tl = bx; tl < NTILES; tl += F_NC) {
    asm volatile("s_waitcnt vmcnt(8)" ::: "memory");
    __builtin_amdgcn_s_barrier();
    __builtin_amdgcn_s_barrier();
    int nx = tl + 2 * F_NC;
    if (nx >= NTILES) nx = bx;
    STAGE(cur, nx)
    cur ^= 1;
  }
#undef STAGE
}

// ---------------- DIAG ablB: R6 GEMM, MFMA sunk, no stash -------------------
__global__ __launch_bounds__(256, 2) void filter_ablB_kernel(
    const __bf16* __restrict__ memn, const __bf16* __restrict__ z_n) {
  __shared__ __bf16 tile[2][64 * 256];
  const int t = threadIdx.x;
  const int w = t >> 6;
  const int l = t & 63;
  const int c = l & 15;
  const int lg = l >> 4;
  const int bx = blockIdx.x;
  const int bbase = blockIdx.y * 256 + w * 64 + c;

  f32x4 zr[4][8];
#pragma unroll
  for (int s = 0; s < 4; ++s)
#pragma unroll
    for (int kc = 0; kc < 8; ++kc)
      zr[s][kc] = *(const f32x4*)(z_n + (size_t)(bbase + s * 16) * D_N +
                                  kc * 32 + lg * 8);
#pragma unroll
  for (int s = 0; s < 4; ++s)
#pragma unroll
    for (int kc = 0; kc < 8; ++kc) asm volatile("" : "+v"(zr[s][kc]));

  char* tileb = (char*)tile;
#define STAGE(buf, tl_)                                                       \
  {                                                                           \
    const __bf16* _g = memn + (size_t)((tl_) * 64 + w * 16 + c) * D_N + lg * 8; \
    char* _d = tileb + (buf) * 32768 + w * 8192;                              \
    _Pragma("unroll") for (int i = 0; i < 8; ++i)                             \
        load_lds16(_g + i * 32, _d + i * 1024);                               \
  }
  int cur = 0;
  STAGE(0, bx)
  STAGE(1, bx + F_NC)
  for (int tl = bx; tl < NTILES; tl += F_NC) {
    asm volatile("s_waitcnt vmcnt(8)" ::: "memory");
    __builtin_amdgcn_s_barrier();
    __builtin_amdgcn_sched_barrier(0);
    const char* curb = tileb + cur * 32768;
#pragma unroll
    for (int mf = 0; mf < 4; ++mf) {
      f32x4 acc0 = {0.f, 0.f, 0.f, 0.f};
      f32x4 acc1 = {0.f, 0.f, 0.f, 0.f};
      f32x4 acc2 = {0.f, 0.f, 0.f, 0.f};
      f32x4 acc3 = {0.f, 0.f, 0.f, 0.f};
#pragma unroll
      for (int kc = 0; kc < 8; ++kc) {
        bf16x8 a = *(const bf16x8*)(curb + (mf * 8 + kc) * 1024 + l * 16);
        acc0 = __builtin_amdgcn_mfma_f32_16x16x32_bf16(
            a, __builtin_bit_cast(bf16x8, zr[0][kc]), acc0, 0, 0, 0);
        acc1 = __builtin_amdgcn_mfma_f32_16x16x32_bf16(
            a, __builtin_bit_cast(bf16x8, zr[1][kc]), acc1, 0, 0, 0);
        acc2 = __builtin_amdgcn_mfma_f32_16x16x32_bf16(
            a, __builtin_bit_cast(bf16x8, zr[2][kc]), acc2, 0, 0, 0);
        acc3 = __builtin_amdgcn_mfma_f32_16x16x32_bf16(
            a, __builtin_bit_cast(bf16x8, zr[3][kc]), acc3, 0, 0, 0);
      }
      asm volatile("" :: "v"(acc0), "v"(acc1), "v"(acc2), "v"(acc3));
    }
    asm volatile("s_waitcnt lgkmcnt(0)" ::: "memory");
    __builtin_amdgcn_s_barrier();
    int nx = tl + 2 * F_NC;
    if (nx >= NTILES) nx = bx;
    STAGE(cur, nx)
    cur ^= 1;
  }
#undef STAGE
}

// ---------------- DIAG v0: reg-staged single-LDS-buffer pipeline ------------
// No global_load_lds anywhere -> all waitcnts are compiler-tracked & counted.
__global__ __launch_bounds__(256, 3) void filter_v0_kernel(
    const __bf16* __restrict__ memn, const __bf16* __restrict__ z_n,
    const float* __restrict__ tau, int* __restrict__ cnt,
    float* __restrict__ candv) {
  __shared__ __bf16 tile[64 * 256];  // 32 KB single buffer
  const int t = threadIdx.x;
  const int w = t >> 6;
  const int l = t & 63;
  const int c = l & 15;
  const int lg = l >> 4;
  const int bx = blockIdx.x;
  const int bbase = blockIdx.y * 256 + w * 64 + c;

  f32x4 zr[4][8];
#pragma unroll
  for (int s = 0; s < 4; ++s)
#pragma unroll
    for (int kc = 0; kc < 8; ++kc)
      zr[s][kc] = *(const f32x4*)(z_n + (size_t)(bbase + s * 16) * D_N +
                                  kc * 32 + lg * 8);
#pragma unroll
  for (int s = 0; s < 4; ++s)
#pragma unroll
    for (int kc = 0; kc < 8; ++kc) asm volatile("" : "+v"(zr[s][kc]));

  float tauv[4];
#pragma unroll
  for (int s = 0; s < 4; ++s) tauv[s] = tau[bbase + s * 16];

  float st0[4], st1[4];
  int nss[4];
#pragma unroll
  for (int s = 0; s < 4; ++s) { st0[s] = 0.f; st1[s] = 0.f; nss[s] = 0; }

  char* tileb = (char*)tile;
  const size_t rowoff = (size_t)(w * 16 + c) * D_N + lg * 8;

  f32x4 stg[8];
  // load + write tile bx
#pragma unroll
  for (int i = 0; i < 8; ++i)
    stg[i] = ((const f32x4*)(memn + (size_t)bx * 64 * D_N + rowoff))[i * 4];
#pragma unroll
  for (int i = 0; i < 8; ++i)
    *(f32x4*)(tileb + (w * 8 + i) * 1024 + l * 16) = stg[i];
  // prefetch tile bx+F_NC into regs
#pragma unroll
  for (int i = 0; i < 8; ++i)
    stg[i] = ((const f32x4*)(memn + (size_t)(bx + F_NC) * 64 * D_N + rowoff))[i * 4];
  asm volatile("s_waitcnt lgkmcnt(0)" ::: "memory");
  __builtin_amdgcn_sched_barrier(0);
  __builtin_amdgcn_s_barrier();

  for (int tl = bx; tl < NTILES; tl += F_NC) {
#pragma unroll
    for (int mf = 0; mf < 4; ++mf) {
      f32x4 acc0 = {0.f, 0.f, 0.f, 0.f};
      f32x4 acc1 = {0.f, 0.f, 0.f, 0.f};
      f32x4 acc2 = {0.f, 0.f, 0.f, 0.f};
      f32x4 acc3 = {0.f, 0.f, 0.f, 0.f};
#pragma unroll
      for (int kc = 0; kc < 8; ++kc) {
        bf16x8 a = *(const bf16x8*)(tileb + (mf * 8 + kc) * 1024 + l * 16);
        acc0 = __builtin_amdgcn_mfma_f32_16x16x32_bf16(
            a, __builtin_bit_cast(bf16x8, zr[0][kc]), acc0, 0, 0, 0);
        acc1 = __builtin_amdgcn_mfma_f32_16x16x32_bf16(
            a, __builtin_bit_cast(bf16x8, zr[1][kc]), acc1, 0, 0, 0);
        acc2 = __builtin_amdgcn_mfma_f32_16x16x32_bf16(
            a, __builtin_bit_cast(bf16x8, zr[2][kc]), acc2, 0, 0, 0);
        acc3 = __builtin_amdgcn_mfma_f32_16x16x32_bf16(
            a, __builtin_bit_cast(bf16x8, zr[3][kc]), acc3, 0, 0, 0);
      }
#define STASH(accv, s)                                                        \
      _Pragma("unroll") for (int j = 0; j < 4; ++j) {                         \
        float v = (accv)[j];                                                  \
        if (v >= tauv[s]) {                                                   \
          if (nss[s] == 0) { st0[s] = v; nss[s] = 1; }                        \
          else if (nss[s] == 1) { st1[s] = v; nss[s] = 2; }                   \
          else {                                                              \
            int p = atomicAdd(&cnt[bbase + (s) * 16], 1);                     \
            if (p < CAP) candv[(size_t)(bbase + (s) * 16) * CAP + p] = v;     \
          }                                                                   \
        }                                                                     \
      }
      STASH(acc0, 0) STASH(acc1, 1) STASH(acc2, 2) STASH(acc3, 3)
#undef STASH
    }
    __builtin_amdgcn_s_barrier();   // all waves done reading tile
    if (tl + F_NC < NTILES) {
#pragma unroll
      for (int i = 0; i < 8; ++i)
        *(f32x4*)(tileb + (w * 8 + i) * 1024 + l * 16) = stg[i];
      const int nx = tl + 2 * F_NC;
      if (nx < NTILES) {
#pragma unroll
        for (int i = 0; i < 8; ++i)
          stg[i] = ((const f32x4*)(memn + (size_t)nx * 64 * D_N + rowoff))[i * 4];
      }
      asm volatile("s_waitcnt lgkmcnt(0)" ::: "memory");
      __builtin_amdgcn_sched_barrier(0);
      __builtin_amdgcn_s_barrier();
    }
  }

#pragma unroll
  for (int s = 0; s < 4; ++s) {
    if (nss[s] > 0) {
      const int bb = bbase + s * 16;
      int p = atomicAdd(&cnt[bb], nss[s]);
      if (p < CAP) candv[(size_t)bb * CAP + p] = st0[s];
      if (nss[s] == 2 && p + 1 < CAP) candv[(size_t)bb * CAP + p + 1] = st1[s];
    }
  }
}

// ---------------- final: exact top-16 of survivors + combine ----------------
__global__ __launch_bounds__(64) void final_kernel(
    const int* __restrict__ cnt, const float* __restrict__ candv,
    float* __restrict__ out) {
  const int b = blockIdx.x;
  const int l = threadIdx.x;
  const int n = min(cnt[b], CAP);
  float lst[16];
#pragma unroll
  for (int i = 0; i < 16; ++i) lst[i] = -3.0e38f;
  const float* cb = candv + (size_t)b * CAP;
  for (int k = l; k < n; k += 64) topk_insert(lst, cb[k]);

  float sum = 0.0f;
#pragma unroll
  for (int r = 0; r < K_N; ++r) {
    float h = lst[0];
    float g = h;
#pragma unroll
    for (int o = 1; o < 64; o <<= 1) g = fmaxf(g, __shfl_xor(g, o, 64));
    unsigned long long bal = __ballot(h == g);
    int winner = __ffsll(bal) - 1;
    if (l == winner) {
#pragma unroll
      for (int i = 0; i < 15; ++i) lst[i] = lst[i + 1];
      lst[15] = -3.0e38f;
    }
    sum += g;
  }
  float nov = 1.0f - sum / (float)K_N;
  nov = fminf(fmaxf(nov, 0.0f), 1.0f);
  if (l == 0) {
    float pe = out[B_N + b];
    float ep = out[2 * B_N + b];
    out[b] = pe + 0.5f * ep + 0.5f * nov;
    out[3 * B_N + b] = nov;
  }
}

extern "C" void kernel_launch(void* const* d_in, const int* in_sizes, int n_in,
                              void* d_out, int out_size, void* d_ws, size_t ws_size,
                              hipStream_t stream) {
  (void)in_sizes; (void)n_in; (void)out_size; (void)ws_size;
  const float* z_t    = (const float*)d_in[0];
  const float* action = (const float*)d_in[1];
  const float* z_t1   = (const float*)d_in[2];
  const float* sigma  = (const float*)d_in[3];
  const float* mem    = (const float*)d_in[4];
  const float* W1 = (const float*)d_in[5];
  const float* b1 = (const float*)d_in[6];
  const float* g1 = (const float*)d_in[7];
  const float* be1= (const float*)d_in[8];
  const float* W2 = (const float*)d_in[9];
  const float* b2 = (const float*)d_in[10];
  const float* g2 = (const float*)d_in[11];
  const float* be2= (const float*)d_in[12];
  const float* W3 = (const float*)d_in[13];
  const float* b3 = (const float*)d_in[14];
  float* out = (float*)d_out;

  char* ws = (char*)d_ws;
  __bf16* memn  = (__bf16*)ws;                          // 102,400,000 B
  __bf16* z_n   = (__bf16*)(ws + 102400256);            // 524,288 B
  float*  tcand = (float*)(ws + 102924544);             // 2,097,152 B
  float*  tau   = (float*)(ws + 105021696);             // 4,096 B
  int*    cnt   = (int*)(ws + 105025792);               // 4,096 B
  float*  candv = (float*)(ws + 105029888);             // 4,194,304 B

  prep_kernel<<<MEMCVT_BLKS + B_N, 256, 0, stream>>>(
      mem, memn, z_t, action, z_t1, sigma,
      W1, b1, g1, be1, W2, b2, g2, be2, W3, b3, out, z_n);
  prepass_kernel<<<dim3(S_CHUNKS, 8), 512, 0, stream>>>(memn, z_n, tcand);
  tau_kernel<<<B_N, 64, 0, stream>>>(tcand, tau, cnt);
  filter_kernel<<<dim3(F_NC, F_BY), 256, 0, stream>>>(memn, z_n, tau, cnt, candv);
  final_kernel<<<B_N, 64, 0, stream>>>(cnt, candv, out);

  // ---- diagnostics (run AFTER output is complete; cnt/candv are scratch
  // from here on -- deterministic because every call rebuilds them) ----
  filter_ablA_kernel<<<dim3(F_NC, F_BY), 256, 0, stream>>>(memn);
  filter_ablB_kernel<<<dim3(F_NC, F_BY), 256, 0, stream>>>(memn, z_n);
  filter_v0_kernel<<<dim3(F_NC, F_BY), 256, 0, stream>>>(memn, z_n, tau, cnt, candv);
}

// Round 8
// 352.404 us; speedup vs baseline: 2.3430x; 2.3430x over previous
//
#include <hip/hip_runtime.h>
#include <hip/hip_bf16.h>

typedef __bf16 bf16x8 __attribute__((ext_vector_type(8)));
typedef __bf16 bf16x4 __attribute__((ext_vector_type(4)));
typedef float f32x4 __attribute__((ext_vector_type(4)));

#define B_N 1024
#define D_N 256
#define A_N 6
#define M_N 200000
#define K_N 16
#define H1_N 128
#define H2_N 64
#define S_TILES 6       // prepass tiles per chunk
#define S_CHUNKS 32     // prepass chunks -> sample = 32*6*64 = 12288 rows
#define NT32 6250       // 200000 / 32 (filter tiles are 32 rows now)
#define F_NC 256        // filter: m-chunk count (grid.x)
#define F_BY 8          // filter: b-groups of 128 cols (grid.y)
#define CAP 1024        // per-b survivor capacity
#define MEMCVT_BLKS (M_N / 4)

__device__ __forceinline__ float wred_sum(float v) {
#pragma unroll
  for (int o = 1; o < 64; o <<= 1) v += __shfl_xor(v, o, 64);
  return v;
}

// descending top-16 insert; compile-time indices only (stays in VGPRs)
__device__ __forceinline__ void topk_insert(float (&lst)[16], float v) {
  if (v <= lst[15]) return;
#pragma unroll
  for (int i = 0; i < 16; ++i) {
    bool gt = v > lst[i];
    float hi = gt ? v : lst[i];
    v = gt ? lst[i] : v;
    lst[i] = hi;
  }
}

__device__ __forceinline__ void load_lds16(const void* g, void* l) {
  __builtin_amdgcn_global_load_lds(
      (const __attribute__((address_space(1))) unsigned int*)g,
      (__attribute__((address_space(3))) unsigned int*)l, 16, 0, 0);
}

// ---------- fused: memcvt (blocks 0..49999) + forward model (blocks 50000+) -
__global__ __launch_bounds__(256) void prep_kernel(
    const float* __restrict__ mem, __bf16* __restrict__ memn,
    const float* __restrict__ z_t, const float* __restrict__ action,
    const float* __restrict__ z_t1, const float* __restrict__ sigma,
    const float* __restrict__ W1, const float* __restrict__ b1,
    const float* __restrict__ g1, const float* __restrict__ be1,
    const float* __restrict__ W2, const float* __restrict__ b2,
    const float* __restrict__ g2, const float* __restrict__ be2,
    const float* __restrict__ W3, const float* __restrict__ b3,
    float* __restrict__ out, __bf16* __restrict__ z_n) {
  __shared__ float s_inp[D_N + A_N];
  __shared__ float s_h1[H1_N];
  __shared__ float s_h2[H2_N];
  __shared__ float red[8];
  const int t = threadIdx.x;
  const int w = t >> 6;

  if (blockIdx.x < MEMCVT_BLKS) {
    const int l = t & 63;
    const size_t row = (size_t)blockIdx.x * 4 + w;
    const float4 v = ((const float4*)(mem + row * D_N))[l];
    float ss = wred_sum(v.x * v.x + v.y * v.y + v.z * v.z + v.w * v.w);
    const float inv = 1.0f / (sqrtf(ss) + 1e-8f);
    bf16x4 p;
    p[0] = (__bf16)(v.x * inv); p[1] = (__bf16)(v.y * inv);
    p[2] = (__bf16)(v.z * inv); p[3] = (__bf16)(v.w * inv);
    *(bf16x4*)(memn + row * D_N + l * 4) = p;
    return;
  }

  const int b = blockIdx.x - MEMCVT_BLKS;

  float zv = z_t[b * D_N + t];
  s_inp[t] = zv;
  if (t < A_N) s_inp[D_N + t] = action[b * A_N + t];

  float ss = wred_sum(zv * zv);
  if ((t & 63) == 0) red[w] = ss;
  __syncthreads();
  float tot = red[0] + red[1] + red[2] + red[3];
  float invz = 1.0f / (sqrtf(tot) + 1e-8f);
  z_n[b * D_N + t] = (__bf16)(zv * invz);

  float y1 = 0.0f;
  if (t < H1_N) {
    y1 = b1[t];
    for (int k = 0; k < D_N + A_N; ++k) y1 += s_inp[k] * W1[k * H1_N + t];
  }
  __syncthreads();
  float s1 = wred_sum(t < H1_N ? y1 : 0.0f);
  float q1 = wred_sum(t < H1_N ? y1 * y1 : 0.0f);
  if ((t & 63) == 0) { red[w] = s1; red[4 + w] = q1; }
  __syncthreads();
  float S1 = red[0] + red[1] + red[2] + red[3];
  float Q1 = red[4] + red[5] + red[6] + red[7];
  float mu1 = S1 / (float)H1_N;
  float var1 = Q1 / (float)H1_N - mu1 * mu1;
  float rs1 = rsqrtf(var1 + 1e-5f);
  if (t < H1_N) {
    float xn = (y1 - mu1) * rs1;
    s_h1[t] = fmaxf(0.0f, xn * g1[t] + be1[t]);
  }
  __syncthreads();

  float y2 = 0.0f;
  if (t < H2_N) {
    y2 = b2[t];
    for (int k = 0; k < H1_N; ++k) y2 += s_h1[k] * W2[k * H2_N + t];
  }
  __syncthreads();
  float s2 = wred_sum(t < H2_N ? y2 : 0.0f);
  float q2 = wred_sum(t < H2_N ? y2 * y2 : 0.0f);
  if ((t & 63) == 0) { red[w] = s2; red[4 + w] = q2; }
  __syncthreads();
  float S2 = red[0] + red[1] + red[2] + red[3];
  float Q2 = red[4] + red[5] + red[6] + red[7];
  float mu2 = S2 / (float)H2_N;
  float var2 = Q2 / (float)H2_N - mu2 * mu2;
  float rs2 = rsqrtf(var2 + 1e-5f);
  if (t < H2_N) {
    float xn = (y2 - mu2) * rs2;
    s_h2[t] = fmaxf(0.0f, xn * g2[t] + be2[t]);
  }
  __syncthreads();

  float zp = b3[t];
  for (int k = 0; k < H2_N; ++k) zp += s_h2[k] * W3[k * D_N + t];
  float d = zp - z_t1[b * D_N + t];
  __syncthreads();
  float pe = wred_sum(d * d);
  if ((t & 63) == 0) red[w] = pe;
  __syncthreads();
  if (t == 0) {
    float PE = (red[0] + red[1] + red[2] + red[3]) / (float)D_N;
    out[B_N + b] = PE;
    float s6 = 0.0f;
    for (int i = 0; i < A_N; ++i) s6 += sigma[b * A_N + i];
    out[2 * B_N + b] = s6 / (float)A_N;
  }
}

// ---------------- prepass: exact top-16 over 12288-row sample ---------------
__global__ __launch_bounds__(512) void prepass_kernel(
    const __bf16* __restrict__ memn, const __bf16* __restrict__ z_n,
    float* __restrict__ tcand) {
  __shared__ __bf16 tile[64 * 256];
  const int t = threadIdx.x;
  const int w = t >> 6;
  const int l = t & 63;
  const int c = l & 15;
  const int lg = l >> 4;
  const int brow = blockIdx.y * 128 + w * 16 + c;

  bf16x8 zf[8];
#pragma unroll
  for (int kc = 0; kc < 8; ++kc)
    zf[kc] = *(const bf16x8*)(z_n + brow * D_N + kc * 32 + lg * 8);

  float lst[16];
#pragma unroll
  for (int i = 0; i < 16; ++i) lst[i] = -3.0e38f;

  const int sr = t >> 3;
  const int sc = t & 7;
  char* tileb = (char*)tile;

  for (int tl = 0; tl < S_TILES; ++tl) {
    const int m0 = (blockIdx.x * S_TILES + tl) * 64;
#pragma unroll
    for (int i = 0; i < 4; ++i) {
      bf16x8 d = *(const bf16x8*)(memn + (size_t)(m0 + sr) * D_N + sc * 32 + i * 8);
      *(bf16x8*)(tileb + sr * 512 + ((sc * 64 + i * 16) ^ ((sr & 7) << 4))) = d;
    }
    __syncthreads();
#pragma unroll
    for (int mf = 0; mf < 4; ++mf) {
      const int row = mf * 16 + c;
      const int rsw = (row & 7) << 4;
      f32x4 acc = {0.f, 0.f, 0.f, 0.f};
#pragma unroll
      for (int kc = 0; kc < 8; ++kc) {
        const int inner = (kc * 64 + lg * 16) ^ rsw;
        bf16x8 a = *(const bf16x8*)(tileb + row * 512 + inner);
        acc = __builtin_amdgcn_mfma_f32_16x16x32_bf16(a, zf[kc], acc, 0, 0, 0);
      }
      topk_insert(lst, acc[0]);
      topk_insert(lst, acc[1]);
      topk_insert(lst, acc[2]);
      topk_insert(lst, acc[3]);
    }
    __syncthreads();
  }

  float mg[16];
#pragma unroll
  for (int r = 0; r < 16; ++r) {
    float h = lst[0];
    float g = fmaxf(h, __shfl_xor(h, 16, 64));
    g = fmaxf(g, __shfl_xor(g, 32, 64));
    unsigned long long bal = __ballot(h == g);
    unsigned long long grp = (bal >> c) & 0x0001000100010001ULL;
    int fs = __ffsll(grp) - 1;
    if ((lg << 4) == fs) {
#pragma unroll
      for (int i = 0; i < 15; ++i) lst[i] = lst[i + 1];
      lst[15] = -3.0e38f;
    }
    mg[r] = g;
  }
  if (l < 16) {
    float* dst = tcand + ((size_t)brow * S_CHUNKS + blockIdx.x) * 16;
#pragma unroll
    for (int i = 0; i < 16; i += 4) {
      float4 o = make_float4(mg[i], mg[i + 1], mg[i + 2], mg[i + 3]);
      *(float4*)(dst + i) = o;
    }
  }
}

// -------- tau: 16th-largest of the sample candidates (+ zero cnt) -----------
__global__ __launch_bounds__(64) void tau_kernel(
    const float* __restrict__ tcand, float* __restrict__ tau,
    int* __restrict__ cnt) {
  const int b = blockIdx.x;
  const int l = threadIdx.x;
  if (l == 0) cnt[b] = 0;
  float lst[16];
#pragma unroll
  for (int i = 0; i < 16; ++i) lst[i] = -3.0e38f;
  const float* cb = tcand + (size_t)b * (S_CHUNKS * 16);
#pragma unroll
  for (int k = 0; k < (S_CHUNKS * 16) / 64; ++k) topk_insert(lst, cb[k * 64 + l]);

  float g16 = -3.0e38f;
#pragma unroll
  for (int r = 0; r < K_N; ++r) {
    float h = lst[0];
    float g = h;
#pragma unroll
    for (int o = 1; o < 64; o <<= 1) g = fmaxf(g, __shfl_xor(g, o, 64));
    unsigned long long bal = __ballot(h == g);
    int winner = __ffsll(bal) - 1;
    if (l == winner) {
#pragma unroll
      for (int i = 0; i < 15; ++i) lst[i] = lst[i + 1];
      lst[15] = -3.0e38f;
    }
    g16 = g;
  }
  if (l == 0) tau[b] = g16;
}

// ---------------- filter: GEMM + threshold push (z truly resident) ----------
// grid (F_NC=256, F_BY=8); 256 thr = 4 waves x 32 b-cols (2 z-sets/wave).
// z budget: 2 sets x 8 kc x 4 VGPR = 64 VGPRs -- FITS (the R3-R7 versions
// demanded 128 z-VGPRs, which silently spilled/rematerialized every iter).
// 32-row tiles, 2x16KB LDS dbuf, T3-minimum 2-phase, 4-5 blocks/CU TLP.
__global__ __launch_bounds__(256, 4) void filter_kernel(
    const __bf16* __restrict__ memn, const __bf16* __restrict__ z_n,
    const float* __restrict__ tau, int* __restrict__ cnt,
    float* __restrict__ candv) {
  __shared__ __bf16 tile[2][32 * 256];  // 2 x 16 KB, fragment-contiguous
  const int t = threadIdx.x;
  const int w = t >> 6;   // 0..3
  const int l = t & 63;
  const int c = l & 15;
  const int lg = l >> 4;
  const int bx = blockIdx.x;
  const int bbase = blockIdx.y * 128 + w * 32 + c;  // + s*16, s=0..1

  // z fragments: 2 sets x 8 kc, punned to f32x4, pinned (64 VGPRs, resident)
  f32x4 zr[2][8];
#pragma unroll
  for (int s = 0; s < 2; ++s)
#pragma unroll
    for (int kc = 0; kc < 8; ++kc)
      zr[s][kc] = *(const f32x4*)(z_n + (size_t)(bbase + s * 16) * D_N +
                                  kc * 32 + lg * 8);
#pragma unroll
  for (int s = 0; s < 2; ++s)
#pragma unroll
    for (int kc = 0; kc < 8; ++kc) asm volatile("" : "+v"(zr[s][kc]));

  const float tau0 = tau[bbase];
  const float tau1 = tau[bbase + 16];

  char* tileb = (char*)tile;
  // stage 32x256 tile as 16 frag-blocks of 1024B; wave w stages frags w*4+i.
  // frag f: rows (f>>3)*16 + (0..15), col elems (f&7)*32 + halves.
  // staging lane: row += c, col += lg*8; LDS dest lane-linear (m104 rule).
#define STAGE(buf, tl_)                                                       \
  {                                                                           \
    const __bf16* _g = memn + (size_t)((tl_) * 32 + (w >> 1) * 16 + c) * D_N  \
                       + (w & 1) * 128 + lg * 8;                              \
    char* _d = tileb + (buf) * 16384 + w * 4096;                              \
    _Pragma("unroll") for (int i = 0; i < 4; ++i)                             \
        load_lds16(_g + i * 32, _d + i * 1024);                               \
  }

  int cur = 0;
  STAGE(0, bx)
  __syncthreads();

  for (int tl = bx; tl < NT32; tl += F_NC) {
    const int nxt = tl + F_NC;
    if (nxt < NT32) STAGE(cur ^ 1, nxt)
    const char* curb = tileb + cur * 16384;
#pragma unroll
    for (int mf = 0; mf < 2; ++mf) {
      f32x4 acc0 = {0.f, 0.f, 0.f, 0.f};
      f32x4 acc1 = {0.f, 0.f, 0.f, 0.f};
#pragma unroll
      for (int kc = 0; kc < 8; ++kc) {
        bf16x8 a = *(const bf16x8*)(curb + (mf * 8 + kc) * 1024 + l * 16);
        acc0 = __builtin_amdgcn_mfma_f32_16x16x32_bf16(
            a, __builtin_bit_cast(bf16x8, zr[0][kc]), acc0, 0, 0, 0);
        acc1 = __builtin_amdgcn_mfma_f32_16x16x32_bf16(
            a, __builtin_bit_cast(bf16x8, zr[1][kc]), acc1, 0, 0, 0);
      }
      // rare-branch push: max-tree gate, then per-value exact push
      float m0 = fmaxf(fmaxf(acc0[0], acc0[1]), fmaxf(acc0[2], acc0[3]));
      if (m0 >= tau0) {
#pragma unroll
        for (int j = 0; j < 4; ++j) {
          if (acc0[j] >= tau0) {
            int p = atomicAdd(&cnt[bbase], 1);
            if (p < CAP) candv[(size_t)bbase * CAP + p] = acc0[j];
          }
        }
      }
      float m1 = fmaxf(fmaxf(acc1[0], acc1[1]), fmaxf(acc1[2], acc1[3]));
      if (m1 >= tau1) {
#pragma unroll
        for (int j = 0; j < 4; ++j) {
          if (acc1[j] >= tau1) {
            int p = atomicAdd(&cnt[bbase + 16], 1);
            if (p < CAP) candv[(size_t)(bbase + 16) * CAP + p] = acc1[j];
          }
        }
      }
    }
    __syncthreads();
    cur ^= 1;
  }
#undef STAGE
}

// ---------------- final: exact top-16 of survivors + combine ----------------
__global__ __launch_bounds__(64) void final_kernel(
    const int* __restrict__ cnt, const float* __restrict__ candv,
    float* __restrict__ out) {
  const int b = blockIdx.x;
  const int l = threadIdx.x;
  const int n = min(cnt[b], CAP);
  float lst[16];
#pragma unroll
  for (int i = 0; i < 16; ++i) lst[i] = -3.0e38f;
  const float* cb = candv + (size_t)b * CAP;
  for (int k = l; k < n; k += 64) topk_insert(lst, cb[k]);

  float sum = 0.0f;
#pragma unroll
  for (int r = 0; r < K_N; ++r) {
    float h = lst[0];
    float g = h;
#pragma unroll
    for (int o = 1; o < 64; o <<= 1) g = fmaxf(g, __shfl_xor(g, o, 64));
    unsigned long long bal = __ballot(h == g);
    int winner = __ffsll(bal) - 1;
    if (l == winner) {
#pragma unroll
      for (int i = 0; i < 15; ++i) lst[i] = lst[i + 1];
      lst[15] = -3.0e38f;
    }
    sum += g;
  }
  float nov = 1.0f - sum / (float)K_N;
  nov = fminf(fmaxf(nov, 0.0f), 1.0f);
  if (l == 0) {
    float pe = out[B_N + b];
    float ep = out[2 * B_N + b];
    out[b] = pe + 0.5f * ep + 0.5f * nov;
    out[3 * B_N + b] = nov;
  }
}

extern "C" void kernel_launch(void* const* d_in, const int* in_sizes, int n_in,
                              void* d_out, int out_size, void* d_ws, size_t ws_size,
                              hipStream_t stream) {
  (void)in_sizes; (void)n_in; (void)out_size; (void)ws_size;
  const float* z_t    = (const float*)d_in[0];
  const float* action = (const float*)d_in[1];
  const float* z_t1   = (const float*)d_in[2];
  const float* sigma  = (const float*)d_in[3];
  const float* mem    = (const float*)d_in[4];
  const float* W1 = (const float*)d_in[5];
  const float* b1 = (const float*)d_in[6];
  const float* g1 = (const float*)d_in[7];
  const float* be1= (const float*)d_in[8];
  const float* W2 = (const float*)d_in[9];
  const float* b2 = (const float*)d_in[10];
  const float* g2 = (const float*)d_in[11];
  const float* be2= (const float*)d_in[12];
  const float* W3 = (const float*)d_in[13];
  const float* b3 = (const float*)d_in[14];
  float* out = (float*)d_out;

  char* ws = (char*)d_ws;
  __bf16* memn  = (__bf16*)ws;                          // 102,400,000 B
  __bf16* z_n   = (__bf16*)(ws + 102400256);            // 524,288 B
  float*  tcand = (float*)(ws + 102924544);             // 2,097,152 B
  float*  tau   = (float*)(ws + 105021696);             // 4,096 B
  int*    cnt   = (int*)(ws + 105025792);               // 4,096 B
  float*  candv = (float*)(ws + 105029888);             // 4,194,304 B

  prep_kernel<<<MEMCVT_BLKS + B_N, 256, 0, stream>>>(
      mem, memn, z_t, action, z_t1, sigma,
      W1, b1, g1, be1, W2, b2, g2, be2, W3, b3, out, z_n);
  prepass_kernel<<<dim3(S_CHUNKS, 8), 512, 0, stream>>>(memn, z_n, tcand);
  tau_kernel<<<B_N, 64, 0, stream>>>(tcand, tau, cnt);
  filter_kernel<<<dim3(F_NC, F_BY), 256, 0, stream>>>(memn, z_n, tau, cnt, candv);
  final_kernel<<<B_N, 64, 0, stream>>>(cnt, candv, out);
}

// Round 9
// 313.926 us; speedup vs baseline: 2.6302x; 1.1226x over previous
//
#include <hip/hip_runtime.h>
#include <hip/hip_bf16.h>

typedef __bf16 bf16x8 __attribute__((ext_vector_type(8)));
typedef __bf16 bf16x4 __attribute__((ext_vector_type(4)));
typedef float f32x4 __attribute__((ext_vector_type(4)));

#define B_N 1024
#define D_N 256
#define A_N 6
#define M_N 200000
#define K_N 16
#define H1_N 128
#define H2_N 64
#define S_TILES 6       // prepass tiles per chunk
#define S_CHUNKS 32     // prepass chunks -> sample = 32*6*64 = 12288 rows
#define NT32 6250       // 200000 / 32 (filter tiles are 32 rows)
#define F_NC 256        // filter: m-chunk count (grid.x)
#define F_BY 8          // filter: b-groups of 128 cols (grid.y)
#define CAP 1024        // per-b survivor capacity
#define MEMCVT_BLKS (M_N / 4)

__device__ __forceinline__ float wred_sum(float v) {
#pragma unroll
  for (int o = 1; o < 64; o <<= 1) v += __shfl_xor(v, o, 64);
  return v;
}

// descending top-16 insert; compile-time indices only (stays in VGPRs)
__device__ __forceinline__ void topk_insert(float (&lst)[16], float v) {
  if (v <= lst[15]) return;
#pragma unroll
  for (int i = 0; i < 16; ++i) {
    bool gt = v > lst[i];
    float hi = gt ? v : lst[i];
    v = gt ? lst[i] : v;
    lst[i] = hi;
  }
}

__device__ __forceinline__ void load_lds16(const void* g, void* l) {
  __builtin_amdgcn_global_load_lds(
      (const __attribute__((address_space(1))) unsigned int*)g,
      (__attribute__((address_space(3))) unsigned int*)l, 16, 0, 0);
}

// ---------- fused: memcvt (blocks 0..49999) + forward model (blocks 50000+) -
__global__ __launch_bounds__(256) void prep_kernel(
    const float* __restrict__ mem, __bf16* __restrict__ memn,
    const float* __restrict__ z_t, const float* __restrict__ action,
    const float* __restrict__ z_t1, const float* __restrict__ sigma,
    const float* __restrict__ W1, const float* __restrict__ b1,
    const float* __restrict__ g1, const float* __restrict__ be1,
    const float* __restrict__ W2, const float* __restrict__ b2,
    const float* __restrict__ g2, const float* __restrict__ be2,
    const float* __restrict__ W3, const float* __restrict__ b3,
    float* __restrict__ out, __bf16* __restrict__ z_n) {
  __shared__ float s_inp[D_N + A_N];
  __shared__ float s_h1[H1_N];
  __shared__ float s_h2[H2_N];
  __shared__ float red[8];
  const int t = threadIdx.x;
  const int w = t >> 6;

  if (blockIdx.x < MEMCVT_BLKS) {
    const int l = t & 63;
    const size_t row = (size_t)blockIdx.x * 4 + w;
    const float4 v = ((const float4*)(mem + row * D_N))[l];
    float ss = wred_sum(v.x * v.x + v.y * v.y + v.z * v.z + v.w * v.w);
    const float inv = 1.0f / (sqrtf(ss) + 1e-8f);
    bf16x4 p;
    p[0] = (__bf16)(v.x * inv); p[1] = (__bf16)(v.y * inv);
    p[2] = (__bf16)(v.z * inv); p[3] = (__bf16)(v.w * inv);
    *(bf16x4*)(memn + row * D_N + l * 4) = p;
    return;
  }

  const int b = blockIdx.x - MEMCVT_BLKS;

  float zv = z_t[b * D_N + t];
  s_inp[t] = zv;
  if (t < A_N) s_inp[D_N + t] = action[b * A_N + t];

  float ss = wred_sum(zv * zv);
  if ((t & 63) == 0) red[w] = ss;
  __syncthreads();
  float tot = red[0] + red[1] + red[2] + red[3];
  float invz = 1.0f / (sqrtf(tot) + 1e-8f);
  z_n[b * D_N + t] = (__bf16)(zv * invz);

  float y1 = 0.0f;
  if (t < H1_N) {
    y1 = b1[t];
    for (int k = 0; k < D_N + A_N; ++k) y1 += s_inp[k] * W1[k * H1_N + t];
  }
  __syncthreads();
  float s1 = wred_sum(t < H1_N ? y1 : 0.0f);
  float q1 = wred_sum(t < H1_N ? y1 * y1 : 0.0f);
  if ((t & 63) == 0) { red[w] = s1; red[4 + w] = q1; }
  __syncthreads();
  float S1 = red[0] + red[1] + red[2] + red[3];
  float Q1 = red[4] + red[5] + red[6] + red[7];
  float mu1 = S1 / (float)H1_N;
  float var1 = Q1 / (float)H1_N - mu1 * mu1;
  float rs1 = rsqrtf(var1 + 1e-5f);
  if (t < H1_N) {
    float xn = (y1 - mu1) * rs1;
    s_h1[t] = fmaxf(0.0f, xn * g1[t] + be1[t]);
  }
  __syncthreads();

  float y2 = 0.0f;
  if (t < H2_N) {
    y2 = b2[t];
    for (int k = 0; k < H1_N; ++k) y2 += s_h1[k] * W2[k * H2_N + t];
  }
  __syncthreads();
  float s2 = wred_sum(t < H2_N ? y2 : 0.0f);
  float q2 = wred_sum(t < H2_N ? y2 * y2 : 0.0f);
  if ((t & 63) == 0) { red[w] = s2; red[4 + w] = q2; }
  __syncthreads();
  float S2 = red[0] + red[1] + red[2] + red[3];
  float Q2 = red[4] + red[5] + red[6] + red[7];
  float mu2 = S2 / (float)H2_N;
  float var2 = Q2 / (float)H2_N - mu2 * mu2;
  float rs2 = rsqrtf(var2 + 1e-5f);
  if (t < H2_N) {
    float xn = (y2 - mu2) * rs2;
    s_h2[t] = fmaxf(0.0f, xn * g2[t] + be2[t]);
  }
  __syncthreads();

  float zp = b3[t];
  for (int k = 0; k < H2_N; ++k) zp += s_h2[k] * W3[k * D_N + t];
  float d = zp - z_t1[b * D_N + t];
  __syncthreads();
  float pe = wred_sum(d * d);
  if ((t & 63) == 0) red[w] = pe;
  __syncthreads();
  if (t == 0) {
    float PE = (red[0] + red[1] + red[2] + red[3]) / (float)D_N;
    out[B_N + b] = PE;
    float s6 = 0.0f;
    for (int i = 0; i < A_N; ++i) s6 += sigma[b * A_N + i];
    out[2 * B_N + b] = s6 / (float)A_N;
  }
}

// ---------------- prepass: exact top-16 over 12288-row sample ---------------
__global__ __launch_bounds__(512) void prepass_kernel(
    const __bf16* __restrict__ memn, const __bf16* __restrict__ z_n,
    float* __restrict__ tcand) {
  __shared__ __bf16 tile[64 * 256];
  const int t = threadIdx.x;
  const int w = t >> 6;
  const int l = t & 63;
  const int c = l & 15;
  const int lg = l >> 4;
  const int brow = blockIdx.y * 128 + w * 16 + c;

  bf16x8 zf[8];
#pragma unroll
  for (int kc = 0; kc < 8; ++kc)
    zf[kc] = *(const bf16x8*)(z_n + brow * D_N + kc * 32 + lg * 8);

  float lst[16];
#pragma unroll
  for (int i = 0; i < 16; ++i) lst[i] = -3.0e38f;

  const int sr = t >> 3;
  const int sc = t & 7;
  char* tileb = (char*)tile;

  for (int tl = 0; tl < S_TILES; ++tl) {
    const int m0 = (blockIdx.x * S_TILES + tl) * 64;
#pragma unroll
    for (int i = 0; i < 4; ++i) {
      bf16x8 d = *(const bf16x8*)(memn + (size_t)(m0 + sr) * D_N + sc * 32 + i * 8);
      *(bf16x8*)(tileb + sr * 512 + ((sc * 64 + i * 16) ^ ((sr & 7) << 4))) = d;
    }
    __syncthreads();
#pragma unroll
    for (int mf = 0; mf < 4; ++mf) {
      const int row = mf * 16 + c;
      const int rsw = (row & 7) << 4;
      f32x4 acc = {0.f, 0.f, 0.f, 0.f};
#pragma unroll
      for (int kc = 0; kc < 8; ++kc) {
        const int inner = (kc * 64 + lg * 16) ^ rsw;
        bf16x8 a = *(const bf16x8*)(tileb + row * 512 + inner);
        acc = __builtin_amdgcn_mfma_f32_16x16x32_bf16(a, zf[kc], acc, 0, 0, 0);
      }
      topk_insert(lst, acc[0]);
      topk_insert(lst, acc[1]);
      topk_insert(lst, acc[2]);
      topk_insert(lst, acc[3]);
    }
    __syncthreads();
  }

  float mg[16];
#pragma unroll
  for (int r = 0; r < 16; ++r) {
    float h = lst[0];
    float g = fmaxf(h, __shfl_xor(h, 16, 64));
    g = fmaxf(g, __shfl_xor(g, 32, 64));
    unsigned long long bal = __ballot(h == g);
    unsigned long long grp = (bal >> c) & 0x0001000100010001ULL;
    int fs = __ffsll(grp) - 1;
    if ((lg << 4) == fs) {
#pragma unroll
      for (int i = 0; i < 15; ++i) lst[i] = lst[i + 1];
      lst[15] = -3.0e38f;
    }
    mg[r] = g;
  }
  if (l < 16) {
    float* dst = tcand + ((size_t)brow * S_CHUNKS + blockIdx.x) * 16;
#pragma unroll
    for (int i = 0; i < 16; i += 4) {
      float4 o = make_float4(mg[i], mg[i + 1], mg[i + 2], mg[i + 3]);
      *(float4*)(dst + i) = o;
    }
  }
}

// -------- tau: 16th-largest of the sample candidates (+ zero cnt) -----------
__global__ __launch_bounds__(64) void tau_kernel(
    const float* __restrict__ tcand, float* __restrict__ tau,
    int* __restrict__ cnt) {
  const int b = blockIdx.x;
  const int l = threadIdx.x;
  if (l == 0) cnt[b] = 0;
  float lst[16];
#pragma unroll
  for (int i = 0; i < 16; ++i) lst[i] = -3.0e38f;
  const float* cb = tcand + (size_t)b * (S_CHUNKS * 16);
#pragma unroll
  for (int k = 0; k < (S_CHUNKS * 16) / 64; ++k) topk_insert(lst, cb[k * 64 + l]);

  float g16 = -3.0e38f;
#pragma unroll
  for (int r = 0; r < K_N; ++r) {
    float h = lst[0];
    float g = h;
#pragma unroll
    for (int o = 1; o < 64; o <<= 1) g = fmaxf(g, __shfl_xor(g, o, 64));
    unsigned long long bal = __ballot(h == g);
    int winner = __ffsll(bal) - 1;
    if (l == winner) {
#pragma unroll
      for (int i = 0; i < 15; ++i) lst[i] = lst[i + 1];
      lst[15] = -3.0e38f;
    }
    g16 = g;
  }
  if (l == 0) tau[b] = g16;
}

// ---------------- filter: GEMM + threshold stash (z pinned resident) --------
// grid (F_NC=256, F_BY=8); 256 thr = 4 waves x 32 b-cols (2 z-sets/wave).
// Fixes vs R8: (1) asm pin INSIDE the loop -> z loads cannot be rematerialized,
// 64 z-VGPRs stay resident (R8: VGPR=52 proved z was reloaded from L2 every
// iter); (2) R6 register stash reinstated -> no atomicAdd (vmcnt(0) drain!)
// in the steady-state loop (expected pushes were ~1.3/wave-iter in R8).
__global__ __launch_bounds__(256, 4) void filter_kernel(
    const __bf16* __restrict__ memn, const __bf16* __restrict__ z_n,
    const float* __restrict__ tau, int* __restrict__ cnt,
    float* __restrict__ candv) {
  __shared__ __bf16 tile[2][32 * 256];  // 2 x 16 KB, fragment-contiguous
  const int t = threadIdx.x;
  const int w = t >> 6;   // 0..3
  const int l = t & 63;
  const int c = l & 15;
  const int lg = l >> 4;
  const int bx = blockIdx.x;
  const int bbase = blockIdx.y * 128 + w * 32 + c;  // + s*16, s=0..1

  // z fragments: 2 sets x 8 kc = 64 VGPRs
  f32x4 zr[2][8];
#pragma unroll
  for (int s = 0; s < 2; ++s)
#pragma unroll
    for (int kc = 0; kc < 8; ++kc)
      zr[s][kc] = *(const f32x4*)(z_n + (size_t)(bbase + s * 16) * D_N +
                                  kc * 32 + lg * 8);

  const float tau0 = tau[bbase];
  const float tau1 = tau[bbase + 16];

  // per-thread survivor stash (named scalars: rule #20)
  float s0a = 0.f, s0b = 0.f, s1a = 0.f, s1b = 0.f;
  int n0 = 0, n1 = 0;

  char* tileb = (char*)tile;
#define STAGE(buf, tl_)                                                       \
  {                                                                           \
    const __bf16* _g = memn + (size_t)((tl_) * 32 + (w >> 1) * 16 + c) * D_N  \
                       + (w & 1) * 128 + lg * 8;                              \
    char* _d = tileb + (buf) * 16384 + w * 4096;                              \
    _Pragma("unroll") for (int i = 0; i < 4; ++i)                             \
        load_lds16(_g + i * 32, _d + i * 1024);                               \
  }

  int cur = 0;
  STAGE(0, bx)
  __syncthreads();

  for (int tl = bx; tl < NT32; tl += F_NC) {
    const int nxt = tl + F_NC;
    if (nxt < NT32) STAGE(cur ^ 1, nxt)
    // pin z every iteration: value becomes loop-carried through opaque asm,
    // so the compiler cannot re-load it from global memory (R8 failure mode)
#pragma unroll
    for (int s = 0; s < 2; ++s)
#pragma unroll
      for (int kc = 0; kc < 8; ++kc) asm volatile("" : "+v"(zr[s][kc]));
    const char* curb = tileb + cur * 16384;
#pragma unroll
    for (int mf = 0; mf < 2; ++mf) {
      f32x4 acc0 = {0.f, 0.f, 0.f, 0.f};
      f32x4 acc1 = {0.f, 0.f, 0.f, 0.f};
#pragma unroll
      for (int kc = 0; kc < 8; ++kc) {
        bf16x8 a = *(const bf16x8*)(curb + (mf * 8 + kc) * 1024 + l * 16);
        acc0 = __builtin_amdgcn_mfma_f32_16x16x32_bf16(
            a, __builtin_bit_cast(bf16x8, zr[0][kc]), acc0, 0, 0, 0);
        acc1 = __builtin_amdgcn_mfma_f32_16x16x32_bf16(
            a, __builtin_bit_cast(bf16x8, zr[1][kc]), acc1, 0, 0, 0);
      }
      // set 0: max-gate, then stash (overflow -> rare direct push)
      float m0 = fmaxf(fmaxf(acc0[0], acc0[1]), fmaxf(acc0[2], acc0[3]));
      if (m0 >= tau0) {
#pragma unroll
        for (int j = 0; j < 4; ++j) {
          float v = acc0[j];
          if (v >= tau0) {
            if (n0 == 0) { s0a = v; n0 = 1; }
            else if (n0 == 1) { s0b = v; n0 = 2; }
            else {
              int p = atomicAdd(&cnt[bbase], 1);
              if (p < CAP) candv[(size_t)bbase * CAP + p] = v;
            }
          }
        }
      }
      float m1 = fmaxf(fmaxf(acc1[0], acc1[1]), fmaxf(acc1[2], acc1[3]));
      if (m1 >= tau1) {
#pragma unroll
        for (int j = 0; j < 4; ++j) {
          float v = acc1[j];
          if (v >= tau1) {
            if (n1 == 0) { s1a = v; n1 = 1; }
            else if (n1 == 1) { s1b = v; n1 = 2; }
            else {
              int p = atomicAdd(&cnt[bbase + 16], 1);
              if (p < CAP) candv[(size_t)(bbase + 16) * CAP + p] = v;
            }
          }
        }
      }
    }
    __syncthreads();
    cur ^= 1;
  }
#undef STAGE

  // deferred flush: atomics only at kernel end
  if (n0 > 0) {
    int p = atomicAdd(&cnt[bbase], n0);
    if (p < CAP) candv[(size_t)bbase * CAP + p] = s0a;
    if (n0 == 2 && p + 1 < CAP) candv[(size_t)bbase * CAP + p + 1] = s0b;
  }
  if (n1 > 0) {
    const int bb = bbase + 16;
    int p = atomicAdd(&cnt[bb], n1);
    if (p < CAP) candv[(size_t)bb * CAP + p] = s1a;
    if (n1 == 2 && p + 1 < CAP) candv[(size_t)bb * CAP + p + 1] = s1b;
  }
}

// ---------------- final: exact top-16 of survivors + combine ----------------
__global__ __launch_bounds__(64) void final_kernel(
    const int* __restrict__ cnt, const float* __restrict__ candv,
    float* __restrict__ out) {
  const int b = blockIdx.x;
  const int l = threadIdx.x;
  const int n = min(cnt[b], CAP);
  float lst[16];
#pragma unroll
  for (int i = 0; i < 16; ++i) lst[i] = -3.0e38f;
  const float* cb = candv + (size_t)b * CAP;
  for (int k = l; k < n; k += 64) topk_insert(lst, cb[k]);

  float sum = 0.0f;
#pragma unroll
  for (int r = 0; r < K_N; ++r) {
    float h = lst[0];
    float g = h;
#pragma unroll
    for (int o = 1; o < 64; o <<= 1) g = fmaxf(g, __shfl_xor(g, o, 64));
    unsigned long long bal = __ballot(h == g);
    int winner = __ffsll(bal) - 1;
    if (l == winner) {
#pragma unroll
      for (int i = 0; i < 15; ++i) lst[i] = lst[i + 1];
      lst[15] = -3.0e38f;
    }
    sum += g;
  }
  float nov = 1.0f - sum / (float)K_N;
  nov = fminf(fmaxf(nov, 0.0f), 1.0f);
  if (l == 0) {
    float pe = out[B_N + b];
    float ep = out[2 * B_N + b];
    out[b] = pe + 0.5f * ep + 0.5f * nov;
    out[3 * B_N + b] = nov;
  }
}

extern "C" void kernel_launch(void* const* d_in, const int* in_sizes, int n_in,
                              void* d_out, int out_size, void* d_ws, size_t ws_size,
                              hipStream_t stream) {
  (void)in_sizes; (void)n_in; (void)out_size; (void)ws_size;
  const float* z_t    = (const float*)d_in[0];
  const float* action = (const float*)d_in[1];
  const float* z_t1   = (const float*)d_in[2];
  const float* sigma  = (const float*)d_in[3];
  const float* mem    = (const float*)d_in[4];
  const float* W1 = (const float*)d_in[5];
  const float* b1 = (const float*)d_in[6];
  const float* g1 = (const float*)d_in[7];
  const float* be1= (const float*)d_in[8];
  const float* W2 = (const float*)d_in[9];
  const float* b2 = (const float*)d_in[10];
  const float* g2 = (const float*)d_in[11];
  const float* be2= (const float*)d_in[12];
  const float* W3 = (const float*)d_in[13];
  const float* b3 = (const float*)d_in[14];
  float* out = (float*)d_out;

  char* ws = (char*)d_ws;
  __bf16* memn  = (__bf16*)ws;                          // 102,400,000 B
  __bf16* z_n   = (__bf16*)(ws + 102400256);            // 524,288 B
  float*  tcand = (float*)(ws + 102924544);             // 2,097,152 B
  float*  tau   = (float*)(ws + 105021696);             // 4,096 B
  int*    cnt   = (int*)(ws + 105025792);               // 4,096 B
  float*  candv = (float*)(ws + 105029888);             // 4,194,304 B

  prep_kernel<<<MEMCVT_BLKS + B_N, 256, 0, stream>>>(
      mem, memn, z_t, action, z_t1, sigma,
      W1, b1, g1, be1, W2, b2, g2, be2, W3, b3, out, z_n);
  prepass_kernel<<<dim3(S_CHUNKS, 8), 512, 0, stream>>>(memn, z_n, tcand);
  tau_kernel<<<B_N, 64, 0, stream>>>(tcand, tau, cnt);
  filter_kernel<<<dim3(F_NC, F_BY), 256, 0, stream>>>(memn, z_n, tau, cnt, candv);
  final_kernel<<<B_N, 64, 0, stream>>>(cnt, candv, out);
}

// Round 10
// 285.555 us; speedup vs baseline: 2.8915x; 1.0994x over previous
//
#include <hip/hip_runtime.h>
#include <hip/hip_bf16.h>

typedef __bf16 bf16x8 __attribute__((ext_vector_type(8)));
typedef __bf16 bf16x4 __attribute__((ext_vector_type(4)));
typedef float f32x4 __attribute__((ext_vector_type(4)));

#define B_N 1024
#define D_N 256
#define A_N 6
#define M_N 200000
#define K_N 16
#define H1_N 128
#define H2_N 64
#define S_TILES 6       // prepass tiles per chunk (64-row tiles)
#define S_CHUNKS 32     // prepass chunks -> sample = 32*6*64 = 12288 rows
#define NT32 6250       // 200000 / 32 (filter tiles are 32 rows)
#define F_NC 128        // filter: m-chunk count (grid.x)
#define F_BY 4          // filter: b-groups of 256 cols (grid.y)
#define CAP 1024        // per-b survivor capacity
#define MEMCVT_BLKS (M_N / 4)

// memn is stored in MFMA-FRAGMENT ORDER: for 16-row group g, k-chunk kc
// (32 cols), frag index f = g*8 + kc occupies bytes [f*1024, f*1024+1024):
// byte l*16+j*2 holds element (row = g*16 + (l&15), col = kc*32 + (l>>4)*8 + j).
// Staging a fragment = ONE contiguous 1KB global_load_lds (lane l -> l*16).

__device__ __forceinline__ float wred_sum(float v) {
#pragma unroll
  for (int o = 1; o < 64; o <<= 1) v += __shfl_xor(v, o, 64);
  return v;
}

// descending top-16 insert; compile-time indices only (stays in VGPRs)
__device__ __forceinline__ void topk_insert(float (&lst)[16], float v) {
  if (v <= lst[15]) return;
#pragma unroll
  for (int i = 0; i < 16; ++i) {
    bool gt = v > lst[i];
    float hi = gt ? v : lst[i];
    v = gt ? lst[i] : v;
    lst[i] = hi;
  }
}

__device__ __forceinline__ void load_lds16(const void* g, void* l) {
  __builtin_amdgcn_global_load_lds(
      (const __attribute__((address_space(1))) unsigned int*)g,
      (__attribute__((address_space(3))) unsigned int*)l, 16, 0, 0);
}

// ---------- fused: memcvt (blocks 0..49999) + forward model (blocks 50000+) -
__global__ __launch_bounds__(256) void prep_kernel(
    const float* __restrict__ mem, __bf16* __restrict__ memn,
    const float* __restrict__ z_t, const float* __restrict__ action,
    const float* __restrict__ z_t1, const float* __restrict__ sigma,
    const float* __restrict__ W1, const float* __restrict__ b1,
    const float* __restrict__ g1, const float* __restrict__ be1,
    const float* __restrict__ W2, const float* __restrict__ b2,
    const float* __restrict__ g2, const float* __restrict__ be2,
    const float* __restrict__ W3, const float* __restrict__ b3,
    float* __restrict__ out, __bf16* __restrict__ z_n) {
  __shared__ float s_inp[D_N + A_N];
  __shared__ float s_h1[H1_N];
  __shared__ float s_h2[H2_N];
  __shared__ float red[8];
  const int t = threadIdx.x;
  const int w = t >> 6;

  if (blockIdx.x < MEMCVT_BLKS) {
    // mem row-norm + bf16 convert, written in FRAGMENT ORDER
    const int l = t & 63;
    const size_t row = (size_t)blockIdx.x * 4 + w;
    const float4 v = ((const float4*)(mem + row * D_N))[l];
    float ss = wred_sum(v.x * v.x + v.y * v.y + v.z * v.z + v.w * v.w);
    const float inv = 1.0f / (sqrtf(ss) + 1e-8f);
    bf16x4 p;
    p[0] = (__bf16)(v.x * inv); p[1] = (__bf16)(v.y * inv);
    p[2] = (__bf16)(v.z * inv); p[3] = (__bf16)(v.w * inv);
    // lane l holds cols 4l..4l+3 of `row`; fragment-order destination:
    char* dst = (char*)memn +
                ((size_t)(row >> 4) * 8 + (l >> 3)) * 1024 +
                (((int)(row & 15)) + (((l & 7) >> 1) << 4)) * 16 + (l & 1) * 8;
    *(bf16x4*)dst = p;
    return;
  }

  const int b = blockIdx.x - MEMCVT_BLKS;

  float zv = z_t[b * D_N + t];
  s_inp[t] = zv;
  if (t < A_N) s_inp[D_N + t] = action[b * A_N + t];

  float ss = wred_sum(zv * zv);
  if ((t & 63) == 0) red[w] = ss;
  __syncthreads();
  float tot = red[0] + red[1] + red[2] + red[3];
  float invz = 1.0f / (sqrtf(tot) + 1e-8f);
  z_n[b * D_N + t] = (__bf16)(zv * invz);

  float y1 = 0.0f;
  if (t < H1_N) {
    y1 = b1[t];
    for (int k = 0; k < D_N + A_N; ++k) y1 += s_inp[k] * W1[k * H1_N + t];
  }
  __syncthreads();
  float s1 = wred_sum(t < H1_N ? y1 : 0.0f);
  float q1 = wred_sum(t < H1_N ? y1 * y1 : 0.0f);
  if ((t & 63) == 0) { red[w] = s1; red[4 + w] = q1; }
  __syncthreads();
  float S1 = red[0] + red[1] + red[2] + red[3];
  float Q1 = red[4] + red[5] + red[6] + red[7];
  float mu1 = S1 / (float)H1_N;
  float var1 = Q1 / (float)H1_N - mu1 * mu1;
  float rs1 = rsqrtf(var1 + 1e-5f);
  if (t < H1_N) {
    float xn = (y1 - mu1) * rs1;
    s_h1[t] = fmaxf(0.0f, xn * g1[t] + be1[t]);
  }
  __syncthreads();

  float y2 = 0.0f;
  if (t < H2_N) {
    y2 = b2[t];
    for (int k = 0; k < H1_N; ++k) y2 += s_h1[k] * W2[k * H2_N + t];
  }
  __syncthreads();
  float s2 = wred_sum(t < H2_N ? y2 : 0.0f);
  float q2 = wred_sum(t < H2_N ? y2 * y2 : 0.0f);
  if ((t & 63) == 0) { red[w] = s2; red[4 + w] = q2; }
  __syncthreads();
  float S2 = red[0] + red[1] + red[2] + red[3];
  float Q2 = red[4] + red[5] + red[6] + red[7];
  float mu2 = S2 / (float)H2_N;
  float var2 = Q2 / (float)H2_N - mu2 * mu2;
  float rs2 = rsqrtf(var2 + 1e-5f);
  if (t < H2_N) {
    float xn = (y2 - mu2) * rs2;
    s_h2[t] = fmaxf(0.0f, xn * g2[t] + be2[t]);
  }
  __syncthreads();

  float zp = b3[t];
  for (int k = 0; k < H2_N; ++k) zp += s_h2[k] * W3[k * D_N + t];
  float d = zp - z_t1[b * D_N + t];
  __syncthreads();
  float pe = wred_sum(d * d);
  if ((t & 63) == 0) red[w] = pe;
  __syncthreads();
  if (t == 0) {
    float PE = (red[0] + red[1] + red[2] + red[3]) / (float)D_N;
    out[B_N + b] = PE;
    float s6 = 0.0f;
    for (int i = 0; i < A_N; ++i) s6 += sigma[b * A_N + i];
    out[2 * B_N + b] = s6 / (float)A_N;
  }
}

// ---------------- prepass: exact top-16 over 12288-row sample ---------------
// grid (S_CHUNKS, 8), 512 thr = 8 waves x 16 b-cols; fragment staging.
__global__ __launch_bounds__(512) void prepass_kernel(
    const __bf16* __restrict__ memn, const __bf16* __restrict__ z_n,
    float* __restrict__ tcand) {
  __shared__ __bf16 tile[64 * 256];  // 32 frags x 1024 B
  const int t = threadIdx.x;
  const int w = t >> 6;
  const int l = t & 63;
  const int c = l & 15;
  const int lg = l >> 4;
  const int brow = blockIdx.y * 128 + w * 16 + c;

  bf16x8 zf[8];
#pragma unroll
  for (int kc = 0; kc < 8; ++kc)
    zf[kc] = *(const bf16x8*)(z_n + brow * D_N + kc * 32 + lg * 8);

  float lst[16];
#pragma unroll
  for (int i = 0; i < 16; ++i) lst[i] = -3.0e38f;

  char* tileb = (char*)tile;
  const char* fragb = (const char*)memn;

  for (int tl = 0; tl < S_TILES; ++tl) {
    // 64-row tile = frags [g0*8, g0*8+32), g0 = tile's first 16-row group
    const size_t f0 = (size_t)(blockIdx.x * S_TILES + tl) * 32;
#pragma unroll
    for (int i = 0; i < 4; ++i) {
      const int f = w * 4 + i;
      load_lds16(fragb + (f0 + f) * 1024 + l * 16, tileb + f * 1024);
    }
    __syncthreads();
#pragma unroll
    for (int mf = 0; mf < 4; ++mf) {
      f32x4 acc = {0.f, 0.f, 0.f, 0.f};
#pragma unroll
      for (int kc = 0; kc < 8; ++kc) {
        bf16x8 a = *(const bf16x8*)(tileb + (mf * 8 + kc) * 1024 + l * 16);
        acc = __builtin_amdgcn_mfma_f32_16x16x32_bf16(a, zf[kc], acc, 0, 0, 0);
      }
      topk_insert(lst, acc[0]);
      topk_insert(lst, acc[1]);
      topk_insert(lst, acc[2]);
      topk_insert(lst, acc[3]);
    }
    __syncthreads();
  }

  // merge the 4 lanes (lg=0..3) sharing b-column c -> exact chunk top-16
  float mg[16];
#pragma unroll
  for (int r = 0; r < 16; ++r) {
    float h = lst[0];
    float g = fmaxf(h, __shfl_xor(h, 16, 64));
    g = fmaxf(g, __shfl_xor(g, 32, 64));
    unsigned long long bal = __ballot(h == g);
    unsigned long long grp = (bal >> c) & 0x0001000100010001ULL;
    int fs = __ffsll(grp) - 1;
    if ((lg << 4) == fs) {
#pragma unroll
      for (int i = 0; i < 15; ++i) lst[i] = lst[i + 1];
      lst[15] = -3.0e38f;
    }
    mg[r] = g;
  }
  if (l < 16) {
    float* dst = tcand + ((size_t)brow * S_CHUNKS + blockIdx.x) * 16;
#pragma unroll
    for (int i = 0; i < 16; i += 4) {
      float4 o = make_float4(mg[i], mg[i + 1], mg[i + 2], mg[i + 3]);
      *(float4*)(dst + i) = o;
    }
  }
}

// -------- tau: 16th-largest of the sample candidates (+ zero cnt) -----------
__global__ __launch_bounds__(64) void tau_kernel(
    const float* __restrict__ tcand, float* __restrict__ tau,
    int* __restrict__ cnt) {
  const int b = blockIdx.x;
  const int l = threadIdx.x;
  if (l == 0) cnt[b] = 0;
  float lst[16];
#pragma unroll
  for (int i = 0; i < 16; ++i) lst[i] = -3.0e38f;
  const float* cb = tcand + (size_t)b * (S_CHUNKS * 16);
#pragma unroll
  for (int k = 0; k < (S_CHUNKS * 16) / 64; ++k) topk_insert(lst, cb[k * 64 + l]);

  float g16 = -3.0e38f;
#pragma unroll
  for (int r = 0; r < K_N; ++r) {
    float h = lst[0];
    float g = h;
#pragma unroll
    for (int o = 1; o < 64; o <<= 1) g = fmaxf(g, __shfl_xor(g, o, 64));
    unsigned long long bal = __ballot(h == g);
    int winner = __ffsll(bal) - 1;
    if (l == winner) {
#pragma unroll
      for (int i = 0; i < 15; ++i) lst[i] = lst[i + 1];
      lst[15] = -3.0e38f;
    }
    g16 = g;
  }
  if (l == 0) tau[b] = g16;
}

// ---------------- filter: contiguous-frag staging, depth-4 ring -------------
// grid (F_NC=128, F_BY=4) = 512 blocks (ALL resident, 2/CU); 512 thr =
// 8 waves x 32 b-cols (2 z-sets = 64 z-VGPRs, fits the 128 cap).
// Staging: each instr loads ONE contiguous 1KB fragment (pre-swizzled memn)
// -- fixes the 16x64B scatter every prior round had. Depth-4 counted vmcnt(6)
// ring (never 0): ~3 compute phases of latency tolerance. R6 stash: no
// steady-state atomics.
__global__ __launch_bounds__(512, 4) void filter_kernel(
    const __bf16* __restrict__ memn, const __bf16* __restrict__ z_n,
    const float* __restrict__ tau, int* __restrict__ cnt,
    float* __restrict__ candv) {
  __shared__ __bf16 tile[4][32 * 256];  // 4 x 16 KB ring
  const int t = threadIdx.x;
  const int w = t >> 6;   // 0..7
  const int l = t & 63;
  const int c = l & 15;
  const int lg = l >> 4;
  const int bx = blockIdx.x;
  const int bbase = blockIdx.y * 256 + w * 32 + c;  // + s*16, s=0..1

  f32x4 zr[2][8];  // 64 VGPRs
#pragma unroll
  for (int s = 0; s < 2; ++s)
#pragma unroll
    for (int kc = 0; kc < 8; ++kc)
      zr[s][kc] = *(const f32x4*)(z_n + (size_t)(bbase + s * 16) * D_N +
                                  kc * 32 + lg * 8);

  const float tau0 = tau[bbase];
  const float tau1 = tau[bbase + 16];

  float s0a = 0.f, s0b = 0.f, s1a = 0.f, s1b = 0.f;
  int n0 = 0, n1 = 0;

  char* tileb = (char*)tile;
  const char* fragb = (const char*)memn;
  // tile tl_ = frags [tl_*16, tl_*16+16); wave w stages frags w*2, w*2+1
#define STAGE(buf, tl_)                                                       \
  {                                                                           \
    const char* _g = fragb + ((size_t)(tl_) * 16 + w * 2) * 1024 + l * 16;    \
    char* _d = tileb + (buf) * 16384 + w * 2048;                              \
    load_lds16(_g, _d);                                                       \
    load_lds16(_g + 1024, _d + 1024);                                         \
  }

  STAGE(0, bx)
  STAGE(1, bx + F_NC)
  STAGE(2, bx + 2 * F_NC)
  STAGE(3, bx + 3 * F_NC)   // bx+384 <= 511 < NT32, always valid

  int it = 0;
  for (int tl = bx; tl < NT32; tl += F_NC, ++it) {
    // retire oldest staged batch (2 loads/thread) + any stash-overflow pushes;
    // 3 newer batches stay in flight (T4: never vmcnt(0) in the loop)
    asm volatile("s_waitcnt vmcnt(6)" ::: "memory");
    __builtin_amdgcn_s_barrier();
    __builtin_amdgcn_sched_barrier(0);
#pragma unroll
    for (int s = 0; s < 2; ++s)
#pragma unroll
      for (int kc = 0; kc < 8; ++kc) asm volatile("" : "+v"(zr[s][kc]));
    const char* curb = tileb + (it & 3) * 16384;
#pragma unroll
    for (int mf = 0; mf < 2; ++mf) {
      f32x4 acc0 = {0.f, 0.f, 0.f, 0.f};
      f32x4 acc1 = {0.f, 0.f, 0.f, 0.f};
#pragma unroll
      for (int kc = 0; kc < 8; ++kc) {
        bf16x8 a = *(const bf16x8*)(curb + (mf * 8 + kc) * 1024 + l * 16);
        acc0 = __builtin_amdgcn_mfma_f32_16x16x32_bf16(
            a, __builtin_bit_cast(bf16x8, zr[0][kc]), acc0, 0, 0, 0);
        acc1 = __builtin_amdgcn_mfma_f32_16x16x32_bf16(
            a, __builtin_bit_cast(bf16x8, zr[1][kc]), acc1, 0, 0, 0);
      }
      float m0 = fmaxf(fmaxf(acc0[0], acc0[1]), fmaxf(acc0[2], acc0[3]));
      if (m0 >= tau0) {
#pragma unroll
        for (int j = 0; j < 4; ++j) {
          float v = acc0[j];
          if (v >= tau0) {
            if (n0 == 0) { s0a = v; n0 = 1; }
            else if (n0 == 1) { s0b = v; n0 = 2; }
            else {
              int p = atomicAdd(&cnt[bbase], 1);
              if (p < CAP) candv[(size_t)bbase * CAP + p] = v;
            }
          }
        }
      }
      float m1 = fmaxf(fmaxf(acc1[0], acc1[1]), fmaxf(acc1[2], acc1[3]));
      if (m1 >= tau1) {
#pragma unroll
        for (int j = 0; j < 4; ++j) {
          float v = acc1[j];
          if (v >= tau1) {
            if (n1 == 0) { s1a = v; n1 = 1; }
            else if (n1 == 1) { s1b = v; n1 = 2; }
            else {
              int p = atomicAdd(&cnt[bbase + 16], 1);
              if (p < CAP) candv[(size_t)(bbase + 16) * CAP + p] = v;
            }
          }
        }
      }
    }
    asm volatile("s_waitcnt lgkmcnt(0)" ::: "memory");
    __builtin_amdgcn_s_barrier();   // WAR: all waves done reading buf[it&3]
    int nx = tl + 4 * F_NC;
    if (nx >= NT32) nx = bx;        // dummy stage keeps vmcnt math exact
    STAGE(it & 3, nx)
  }
#undef STAGE

  // deferred flush: atomics only at kernel end
  if (n0 > 0) {
    int p = atomicAdd(&cnt[bbase], n0);
    if (p < CAP) candv[(size_t)bbase * CAP + p] = s0a;
    if (n0 == 2 && p + 1 < CAP) candv[(size_t)bbase * CAP + p + 1] = s0b;
  }
  if (n1 > 0) {
    const int bb = bbase + 16;
    int p = atomicAdd(&cnt[bb], n1);
    if (p < CAP) candv[(size_t)bb * CAP + p] = s1a;
    if (n1 == 2 && p + 1 < CAP) candv[(size_t)bb * CAP + p + 1] = s1b;
  }
}

// ---------------- final: exact top-16 of survivors + combine ----------------
__global__ __launch_bounds__(64) void final_kernel(
    const int* __restrict__ cnt, const float* __restrict__ candv,
    float* __restrict__ out) {
  const int b = blockIdx.x;
  const int l = threadIdx.x;
  const int n = min(cnt[b], CAP);
  float lst[16];
#pragma unroll
  for (int i = 0; i < 16; ++i) lst[i] = -3.0e38f;
  const float* cb = candv + (size_t)b * CAP;
  for (int k = l; k < n; k += 64) topk_insert(lst, cb[k]);

  float sum = 0.0f;
#pragma unroll
  for (int r = 0; r < K_N; ++r) {
    float h = lst[0];
    float g = h;
#pragma unroll
    for (int o = 1; o < 64; o <<= 1) g = fmaxf(g, __shfl_xor(g, o, 64));
    unsigned long long bal = __ballot(h == g);
    int winner = __ffsll(bal) - 1;
    if (l == winner) {
#pragma unroll
      for (int i = 0; i < 15; ++i) lst[i] = lst[i + 1];
      lst[15] = -3.0e38f;
    }
    sum += g;
  }
  float nov = 1.0f - sum / (float)K_N;
  nov = fminf(fmaxf(nov, 0.0f), 1.0f);
  if (l == 0) {
    float pe = out[B_N + b];
    float ep = out[2 * B_N + b];
    out[b] = pe + 0.5f * ep + 0.5f * nov;
    out[3 * B_N + b] = nov;
  }
}

extern "C" void kernel_launch(void* const* d_in, const int* in_sizes, int n_in,
                              void* d_out, int out_size, void* d_ws, size_t ws_size,
                              hipStream_t stream) {
  (void)in_sizes; (void)n_in; (void)out_size; (void)ws_size;
  const float* z_t    = (const float*)d_in[0];
  const float* action = (const float*)d_in[1];
  const float* z_t1   = (const float*)d_in[2];
  const float* sigma  = (const float*)d_in[3];
  const float* mem    = (const float*)d_in[4];
  const float* W1 = (const float*)d_in[5];
  const float* b1 = (const float*)d_in[6];
  const float* g1 = (const float*)d_in[7];
  const float* be1= (const float*)d_in[8];
  const float* W2 = (const float*)d_in[9];
  const float* b2 = (const float*)d_in[10];
  const float* g2 = (const float*)d_in[11];
  const float* be2= (const float*)d_in[12];
  const float* W3 = (const float*)d_in[13];
  const float* b3 = (const float*)d_in[14];
  float* out = (float*)d_out;

  char* ws = (char*)d_ws;
  __bf16* memn  = (__bf16*)ws;                          // 102,400,000 B (frag order)
  __bf16* z_n   = (__bf16*)(ws + 102400256);            // 524,288 B
  float*  tcand = (float*)(ws + 102924544);             // 2,097,152 B
  float*  tau   = (float*)(ws + 105021696);             // 4,096 B
  int*    cnt   = (int*)(ws + 105025792);               // 4,096 B
  float*  candv = (float*)(ws + 105029888);             // 4,194,304 B

  prep_kernel<<<MEMCVT_BLKS + B_N, 256, 0, stream>>>(
      mem, memn, z_t, action, z_t1, sigma,
      W1, b1, g1, be1, W2, b2, g2, be2, W3, b3, out, z_n);
  prepass_kernel<<<dim3(S_CHUNKS, 8), 512, 0, stream>>>(memn, z_n, tcand);
  tau_kernel<<<B_N, 64, 0, stream>>>(tcand, tau, cnt);
  filter_kernel<<<dim3(F_NC, F_BY), 512, 0, stream>>>(memn, z_n, tau, cnt, candv);
  final_kernel<<<B_N, 64, 0, stream>>>(cnt, candv, out);
}

// Round 11
// 259.065 us; speedup vs baseline: 3.1872x; 1.1023x over previous
//
#include <hip/hip_runtime.h>
#include <hip/hip_bf16.h>

typedef __bf16 bf16x8 __attribute__((ext_vector_type(8)));
typedef __bf16 bf16x4 __attribute__((ext_vector_type(4)));
typedef float f32x4 __attribute__((ext_vector_type(4)));

#define B_N 1024
#define D_N 256
#define A_N 6
#define M_N 200000
#define K_N 16
#define H1_N 128
#define H2_N 64
#define S_TILES 6       // prepass tiles per chunk (64-row tiles)
#define S_CHUNKS 32     // prepass chunks -> sample = 32*6*64 = 12288 rows
#define NT32 6250       // 200000 / 32 (filter tiles are 32 rows)
#define F_NC 128        // filter: m-chunk count (grid.x)
#define F_BY 4          // filter: b-groups of 256 cols (grid.y)
#define CAP 1024        // per-b survivor capacity
#define MEMCVT_BLKS (M_N / 16)   // 12500: 16 rows per block

// memn is stored in MFMA-FRAGMENT ORDER: for 16-row group g, k-chunk kc
// (32 cols), frag index f = g*8 + kc occupies bytes [f*1024, f*1024+1024):
// byte l*16+j*2 holds element (row = g*16 + (l&15), col = kc*32 + (l>>4)*8 + j).
// Staging a fragment = ONE contiguous 1KB global_load_lds (lane l -> l*16).

__device__ __forceinline__ float wred_sum(float v) {
#pragma unroll
  for (int o = 1; o < 64; o <<= 1) v += __shfl_xor(v, o, 64);
  return v;
}

// descending top-16 insert; compile-time indices only (stays in VGPRs)
__device__ __forceinline__ void topk_insert(float (&lst)[16], float v) {
  if (v <= lst[15]) return;
#pragma unroll
  for (int i = 0; i < 16; ++i) {
    bool gt = v > lst[i];
    float hi = gt ? v : lst[i];
    v = gt ? lst[i] : v;
    lst[i] = hi;
  }
}

__device__ __forceinline__ void load_lds16(const void* g, void* l) {
  __builtin_amdgcn_global_load_lds(
      (const __attribute__((address_space(1))) unsigned int*)g,
      (__attribute__((address_space(3))) unsigned int*)l, 16, 0, 0);
}

// ---------- fused: memcvt (blocks 0..12499) + forward model (blocks 12500+) -
__global__ __launch_bounds__(256) void prep_kernel(
    const float* __restrict__ mem, __bf16* __restrict__ memn,
    const float* __restrict__ z_t, const float* __restrict__ action,
    const float* __restrict__ z_t1, const float* __restrict__ sigma,
    const float* __restrict__ W1, const float* __restrict__ b1,
    const float* __restrict__ g1, const float* __restrict__ be1,
    const float* __restrict__ W2, const float* __restrict__ b2,
    const float* __restrict__ g2, const float* __restrict__ be2,
    const float* __restrict__ W3, const float* __restrict__ b3,
    float* __restrict__ out, __bf16* __restrict__ z_n) {
  __shared__ float s_inp[D_N + A_N];
  __shared__ float s_h1[H1_N];
  __shared__ float s_h2[H2_N];
  __shared__ float red[8];
  const int t = threadIdx.x;
  const int w = t >> 6;

  if (blockIdx.x < MEMCVT_BLKS) {
    // ---- mem row-norm + bf16 convert, 16 rows/block, fragment-order dest.
    // thread t: row16 = t>>4, cols q*16..q*16+15 (contiguous 64B read).
    // Its 16 bf16 outputs are exactly two 16B frag chunks; the 4 lanes of a
    // wave sharing (q) but differing in row16 write CONTIGUOUS 64B sectors.
    const int row16 = t >> 4;   // 0..15
    const int q = t & 15;
    const size_t grow = (size_t)blockIdx.x * 16 + row16;
    const f32x4* src = (const f32x4*)(mem + grow * D_N + q * 16);
    f32x4 v0 = src[0], v1 = src[1], v2 = src[2], v3 = src[3];
    float ss = v0[0]*v0[0] + v0[1]*v0[1] + v0[2]*v0[2] + v0[3]*v0[3]
             + v1[0]*v1[0] + v1[1]*v1[1] + v1[2]*v1[2] + v1[3]*v1[3]
             + v2[0]*v2[0] + v2[1]*v2[1] + v2[2]*v2[2] + v2[3]*v2[3]
             + v3[0]*v3[0] + v3[1]*v3[1] + v3[2]*v3[2] + v3[3]*v3[3];
    // reduce across the 16 lanes sharing this row (intra-wave)
#pragma unroll
    for (int o = 1; o < 16; o <<= 1) ss += __shfl_xor(ss, o, 64);
    const float inv = 1.0f / (sqrtf(ss) + 1e-8f);
    bf16x8 a, b;
#pragma unroll
    for (int j = 0; j < 4; ++j) {
      a[j]     = (__bf16)(v0[j] * inv);
      a[4 + j] = (__bf16)(v1[j] * inv);
      b[j]     = (__bf16)(v2[j] * inv);
      b[4 + j] = (__bf16)(v3[j] * inv);
    }
    // frag = g*8 + kc, kc = q>>1; chunk j16 = 2*(q&1) (+1 for second half)
    char* fb = (char*)memn + ((size_t)blockIdx.x * 8 + (q >> 1)) * 1024;
    const int j16 = (q & 1) * 2;
    *(bf16x8*)(fb + (row16 + j16 * 16) * 16) = a;
    *(bf16x8*)(fb + (row16 + (j16 + 1) * 16) * 16) = b;
    return;
  }

  const int b = blockIdx.x - MEMCVT_BLKS;

  float zv = z_t[b * D_N + t];
  s_inp[t] = zv;
  if (t < A_N) s_inp[D_N + t] = action[b * A_N + t];

  float ss = wred_sum(zv * zv);
  if ((t & 63) == 0) red[w] = ss;
  __syncthreads();
  float tot = red[0] + red[1] + red[2] + red[3];
  float invz = 1.0f / (sqrtf(tot) + 1e-8f);
  z_n[b * D_N + t] = (__bf16)(zv * invz);

  float y1 = 0.0f;
  if (t < H1_N) {
    y1 = b1[t];
    for (int k = 0; k < D_N + A_N; ++k) y1 += s_inp[k] * W1[k * H1_N + t];
  }
  __syncthreads();
  float s1 = wred_sum(t < H1_N ? y1 : 0.0f);
  float q1 = wred_sum(t < H1_N ? y1 * y1 : 0.0f);
  if ((t & 63) == 0) { red[w] = s1; red[4 + w] = q1; }
  __syncthreads();
  float S1 = red[0] + red[1] + red[2] + red[3];
  float Q1 = red[4] + red[5] + red[6] + red[7];
  float mu1 = S1 / (float)H1_N;
  float var1 = Q1 / (float)H1_N - mu1 * mu1;
  float rs1 = rsqrtf(var1 + 1e-5f);
  if (t < H1_N) {
    float xn = (y1 - mu1) * rs1;
    s_h1[t] = fmaxf(0.0f, xn * g1[t] + be1[t]);
  }
  __syncthreads();

  float y2 = 0.0f;
  if (t < H2_N) {
    y2 = b2[t];
    for (int k = 0; k < H1_N; ++k) y2 += s_h1[k] * W2[k * H2_N + t];
  }
  __syncthreads();
  float s2 = wred_sum(t < H2_N ? y2 : 0.0f);
  float q2 = wred_sum(t < H2_N ? y2 * y2 : 0.0f);
  if ((t & 63) == 0) { red[w] = s2; red[4 + w] = q2; }
  __syncthreads();
  float S2 = red[0] + red[1] + red[2] + red[3];
  float Q2 = red[4] + red[5] + red[6] + red[7];
  float mu2 = S2 / (float)H2_N;
  float var2 = Q2 / (float)H2_N - mu2 * mu2;
  float rs2 = rsqrtf(var2 + 1e-5f);
  if (t < H2_N) {
    float xn = (y2 - mu2) * rs2;
    s_h2[t] = fmaxf(0.0f, xn * g2[t] + be2[t]);
  }
  __syncthreads();

  float zp = b3[t];
  for (int k = 0; k < H2_N; ++k) zp += s_h2[k] * W3[k * D_N + t];
  float d = zp - z_t1[b * D_N + t];
  __syncthreads();
  float pe = wred_sum(d * d);
  if ((t & 63) == 0) red[w] = pe;
  __syncthreads();
  if (t == 0) {
    float PE = (red[0] + red[1] + red[2] + red[3]) / (float)D_N;
    out[B_N + b] = PE;
    float s6 = 0.0f;
    for (int i = 0; i < A_N; ++i) s6 += sigma[b * A_N + i];
    out[2 * B_N + b] = s6 / (float)A_N;
  }
}

// ---------------- prepass: exact top-16 over 12288-row sample ---------------
// grid (S_CHUNKS, 8), 512 thr = 8 waves x 16 b-cols; fragment staging.
__global__ __launch_bounds__(512) void prepass_kernel(
    const __bf16* __restrict__ memn, const __bf16* __restrict__ z_n,
    float* __restrict__ tcand) {
  __shared__ __bf16 tile[64 * 256];  // 32 frags x 1024 B
  const int t = threadIdx.x;
  const int w = t >> 6;
  const int l = t & 63;
  const int c = l & 15;
  const int lg = l >> 4;
  const int brow = blockIdx.y * 128 + w * 16 + c;

  bf16x8 zf[8];
#pragma unroll
  for (int kc = 0; kc < 8; ++kc)
    zf[kc] = *(const bf16x8*)(z_n + brow * D_N + kc * 32 + lg * 8);

  float lst[16];
#pragma unroll
  for (int i = 0; i < 16; ++i) lst[i] = -3.0e38f;

  char* tileb = (char*)tile;
  const char* fragb = (const char*)memn;

  for (int tl = 0; tl < S_TILES; ++tl) {
    const size_t f0 = (size_t)(blockIdx.x * S_TILES + tl) * 32;
#pragma unroll
    for (int i = 0; i < 4; ++i) {
      const int f = w * 4 + i;
      load_lds16(fragb + (f0 + f) * 1024 + l * 16, tileb + f * 1024);
    }
    __syncthreads();
#pragma unroll
    for (int mf = 0; mf < 4; ++mf) {
      f32x4 acc = {0.f, 0.f, 0.f, 0.f};
#pragma unroll
      for (int kc = 0; kc < 8; ++kc) {
        bf16x8 a = *(const bf16x8*)(tileb + (mf * 8 + kc) * 1024 + l * 16);
        acc = __builtin_amdgcn_mfma_f32_16x16x32_bf16(a, zf[kc], acc, 0, 0, 0);
      }
      topk_insert(lst, acc[0]);
      topk_insert(lst, acc[1]);
      topk_insert(lst, acc[2]);
      topk_insert(lst, acc[3]);
    }
    __syncthreads();
  }

  float mg[16];
#pragma unroll
  for (int r = 0; r < 16; ++r) {
    float h = lst[0];
    float g = fmaxf(h, __shfl_xor(h, 16, 64));
    g = fmaxf(g, __shfl_xor(g, 32, 64));
    unsigned long long bal = __ballot(h == g);
    unsigned long long grp = (bal >> c) & 0x0001000100010001ULL;
    int fs = __ffsll(grp) - 1;
    if ((lg << 4) == fs) {
#pragma unroll
      for (int i = 0; i < 15; ++i) lst[i] = lst[i + 1];
      lst[15] = -3.0e38f;
    }
    mg[r] = g;
  }
  if (l < 16) {
    float* dst = tcand + ((size_t)brow * S_CHUNKS + blockIdx.x) * 16;
#pragma unroll
    for (int i = 0; i < 16; i += 4) {
      float4 o = make_float4(mg[i], mg[i + 1], mg[i + 2], mg[i + 3]);
      *(float4*)(dst + i) = o;
    }
  }
}

// -------- tau: 16th-largest of the sample candidates (+ zero cnt) -----------
__global__ __launch_bounds__(64) void tau_kernel(
    const float* __restrict__ tcand, float* __restrict__ tau,
    int* __restrict__ cnt) {
  const int b = blockIdx.x;
  const int l = threadIdx.x;
  if (l == 0) cnt[b] = 0;
  float lst[16];
#pragma unroll
  for (int i = 0; i < 16; ++i) lst[i] = -3.0e38f;
  const float* cb = tcand + (size_t)b * (S_CHUNKS * 16);
#pragma unroll
  for (int k = 0; k < (S_CHUNKS * 16) / 64; ++k) topk_insert(lst, cb[k * 64 + l]);

  float g16 = -3.0e38f;
#pragma unroll
  for (int r = 0; r < K_N; ++r) {
    float h = lst[0];
    float g = h;
#pragma unroll
    for (int o = 1; o < 64; o <<= 1) g = fmaxf(g, __shfl_xor(g, o, 64));
    unsigned long long bal = __ballot(h == g);
    int winner = __ffsll(bal) - 1;
    if (l == winner) {
#pragma unroll
      for (int i = 0; i < 15; ++i) lst[i] = lst[i + 1];
      lst[15] = -3.0e38f;
    }
    g16 = g;
  }
  if (l == 0) tau[b] = g16;
}

// ---------------- filter: contiguous-frag staging, depth-4 ring -------------
// (FROZEN from R10 -- it left the top-5 there; isolate the prep fix.)
__global__ __launch_bounds__(512, 4) void filter_kernel(
    const __bf16* __restrict__ memn, const __bf16* __restrict__ z_n,
    const float* __restrict__ tau, int* __restrict__ cnt,
    float* __restrict__ candv) {
  __shared__ __bf16 tile[4][32 * 256];  // 4 x 16 KB ring
  const int t = threadIdx.x;
  const int w = t >> 6;   // 0..7
  const int l = t & 63;
  const int c = l & 15;
  const int lg = l >> 4;
  const int bx = blockIdx.x;
  const int bbase = blockIdx.y * 256 + w * 32 + c;  // + s*16, s=0..1

  f32x4 zr[2][8];  // 64 VGPRs
#pragma unroll
  for (int s = 0; s < 2; ++s)
#pragma unroll
    for (int kc = 0; kc < 8; ++kc)
      zr[s][kc] = *(const f32x4*)(z_n + (size_t)(bbase + s * 16) * D_N +
                                  kc * 32 + lg * 8);

  const float tau0 = tau[bbase];
  const float tau1 = tau[bbase + 16];

  float s0a = 0.f, s0b = 0.f, s1a = 0.f, s1b = 0.f;
  int n0 = 0, n1 = 0;

  char* tileb = (char*)tile;
  const char* fragb = (const char*)memn;
#define STAGE(buf, tl_)                                                       \
  {                                                                           \
    const char* _g = fragb + ((size_t)(tl_) * 16 + w * 2) * 1024 + l * 16;    \
    char* _d = tileb + (buf) * 16384 + w * 2048;                              \
    load_lds16(_g, _d);                                                       \
    load_lds16(_g + 1024, _d + 1024);                                         \
  }

  STAGE(0, bx)
  STAGE(1, bx + F_NC)
  STAGE(2, bx + 2 * F_NC)
  STAGE(3, bx + 3 * F_NC)

  int it = 0;
  for (int tl = bx; tl < NT32; tl += F_NC, ++it) {
    asm volatile("s_waitcnt vmcnt(6)" ::: "memory");
    __builtin_amdgcn_s_barrier();
    __builtin_amdgcn_sched_barrier(0);
#pragma unroll
    for (int s = 0; s < 2; ++s)
#pragma unroll
      for (int kc = 0; kc < 8; ++kc) asm volatile("" : "+v"(zr[s][kc]));
    const char* curb = tileb + (it & 3) * 16384;
#pragma unroll
    for (int mf = 0; mf < 2; ++mf) {
      f32x4 acc0 = {0.f, 0.f, 0.f, 0.f};
      f32x4 acc1 = {0.f, 0.f, 0.f, 0.f};
#pragma unroll
      for (int kc = 0; kc < 8; ++kc) {
        bf16x8 a = *(const bf16x8*)(curb + (mf * 8 + kc) * 1024 + l * 16);
        acc0 = __builtin_amdgcn_mfma_f32_16x16x32_bf16(
            a, __builtin_bit_cast(bf16x8, zr[0][kc]), acc0, 0, 0, 0);
        acc1 = __builtin_amdgcn_mfma_f32_16x16x32_bf16(
            a, __builtin_bit_cast(bf16x8, zr[1][kc]), acc1, 0, 0, 0);
      }
      float m0 = fmaxf(fmaxf(acc0[0], acc0[1]), fmaxf(acc0[2], acc0[3]));
      if (m0 >= tau0) {
#pragma unroll
        for (int j = 0; j < 4; ++j) {
          float v = acc0[j];
          if (v >= tau0) {
            if (n0 == 0) { s0a = v; n0 = 1; }
            else if (n0 == 1) { s0b = v; n0 = 2; }
            else {
              int p = atomicAdd(&cnt[bbase], 1);
              if (p < CAP) candv[(size_t)bbase * CAP + p] = v;
            }
          }
        }
      }
      float m1 = fmaxf(fmaxf(acc1[0], acc1[1]), fmaxf(acc1[2], acc1[3]));
      if (m1 >= tau1) {
#pragma unroll
        for (int j = 0; j < 4; ++j) {
          float v = acc1[j];
          if (v >= tau1) {
            if (n1 == 0) { s1a = v; n1 = 1; }
            else if (n1 == 1) { s1b = v; n1 = 2; }
            else {
              int p = atomicAdd(&cnt[bbase + 16], 1);
              if (p < CAP) candv[(size_t)(bbase + 16) * CAP + p] = v;
            }
          }
        }
      }
    }
    asm volatile("s_waitcnt lgkmcnt(0)" ::: "memory");
    __builtin_amdgcn_s_barrier();
    int nx = tl + 4 * F_NC;
    if (nx >= NT32) nx = bx;
    STAGE(it & 3, nx)
  }
#undef STAGE

  if (n0 > 0) {
    int p = atomicAdd(&cnt[bbase], n0);
    if (p < CAP) candv[(size_t)bbase * CAP + p] = s0a;
    if (n0 == 2 && p + 1 < CAP) candv[(size_t)bbase * CAP + p + 1] = s0b;
  }
  if (n1 > 0) {
    const int bb = bbase + 16;
    int p = atomicAdd(&cnt[bb], n1);
    if (p < CAP) candv[(size_t)bb * CAP + p] = s1a;
    if (n1 == 2 && p + 1 < CAP) candv[(size_t)bb * CAP + p + 1] = s1b;
  }
}

// ---------------- final: exact top-16 of survivors + combine ----------------
__global__ __launch_bounds__(64) void final_kernel(
    const int* __restrict__ cnt, const float* __restrict__ candv,
    float* __restrict__ out) {
  const int b = blockIdx.x;
  const int l = threadIdx.x;
  const int n = min(cnt[b], CAP);
  float lst[16];
#pragma unroll
  for (int i = 0; i < 16; ++i) lst[i] = -3.0e38f;
  const float* cb = candv + (size_t)b * CAP;
  for (int k = l; k < n; k += 64) topk_insert(lst, cb[k]);

  float sum = 0.0f;
#pragma unroll
  for (int r = 0; r < K_N; ++r) {
    float h = lst[0];
    float g = h;
#pragma unroll
    for (int o = 1; o < 64; o <<= 1) g = fmaxf(g, __shfl_xor(g, o, 64));
    unsigned long long bal = __ballot(h == g);
    int winner = __ffsll(bal) - 1;
    if (l == winner) {
#pragma unroll
      for (int i = 0; i < 15; ++i) lst[i] = lst[i + 1];
      lst[15] = -3.0e38f;
    }
    sum += g;
  }
  float nov = 1.0f - sum / (float)K_N;
  nov = fminf(fmaxf(nov, 0.0f), 1.0f);
  if (l == 0) {
    float pe = out[B_N + b];
    float ep = out[2 * B_N + b];
    out[b] = pe + 0.5f * ep + 0.5f * nov;
    out[3 * B_N + b] = nov;
  }
}

extern "C" void kernel_launch(void* const* d_in, const int* in_sizes, int n_in,
                              void* d_out, int out_size, void* d_ws, size_t ws_size,
                              hipStream_t stream) {
  (void)in_sizes; (void)n_in; (void)out_size; (void)ws_size;
  const float* z_t    = (const float*)d_in[0];
  const float* action = (const float*)d_in[1];
  const float* z_t1   = (const float*)d_in[2];
  const float* sigma  = (const float*)d_in[3];
  const float* mem    = (const float*)d_in[4];
  const float* W1 = (const float*)d_in[5];
  const float* b1 = (const float*)d_in[6];
  const float* g1 = (const float*)d_in[7];
  const float* be1= (const float*)d_in[8];
  const float* W2 = (const float*)d_in[9];
  const float* b2 = (const float*)d_in[10];
  const float* g2 = (const float*)d_in[11];
  const float* be2= (const float*)d_in[12];
  const float* W3 = (const float*)d_in[13];
  const float* b3 = (const float*)d_in[14];
  float* out = (float*)d_out;

  char* ws = (char*)d_ws;
  __bf16* memn  = (__bf16*)ws;                          // 102,400,000 B (frag order)
  __bf16* z_n   = (__bf16*)(ws + 102400256);            // 524,288 B
  float*  tcand = (float*)(ws + 102924544);             // 2,097,152 B
  float*  tau   = (float*)(ws + 105021696);             // 4,096 B
  int*    cnt   = (int*)(ws + 105025792);               // 4,096 B
  float*  candv = (float*)(ws + 105029888);             // 4,194,304 B

  prep_kernel<<<MEMCVT_BLKS + B_N, 256, 0, stream>>>(
      mem, memn, z_t, action, z_t1, sigma,
      W1, b1, g1, be1, W2, b2, g2, be2, W3, b3, out, z_n);
  prepass_kernel<<<dim3(S_CHUNKS, 8), 512, 0, stream>>>(memn, z_n, tcand);
  tau_kernel<<<B_N, 64, 0, stream>>>(tcand, tau, cnt);
  filter_kernel<<<dim3(F_NC, F_BY), 512, 0, stream>>>(memn, z_n, tau, cnt, candv);
  final_kernel<<<B_N, 64, 0, stream>>>(cnt, candv, out);
}

// Round 12
// 240.034 us; speedup vs baseline: 3.4399x; 1.0793x over previous
//
#include <hip/hip_runtime.h>
#include <hip/hip_bf16.h>

typedef __bf16 bf16x8 __attribute__((ext_vector_type(8)));
typedef __bf16 bf16x4 __attribute__((ext_vector_type(4)));
typedef float f32x4 __attribute__((ext_vector_type(4)));

#define B_N 1024
#define D_N 256
#define A_N 6
#define M_N 200000
#define K_N 16
#define H1_N 128
#define H2_N 64
#define S_TILES 6       // prepass tiles per chunk (64-row tiles)
#define S_CHUNKS 32     // prepass chunks -> sample = 32*6*64 = 12288 rows
#define NT32 6250       // 200000 / 32 (filter tiles are 32 rows)
#define F_NC 128        // filter: m-chunk count (grid.x)
#define F_BY 4          // filter: b-groups of 256 cols (grid.y)
#define CAP 1024        // per-b survivor capacity
#define MEMCVT_BLKS (M_N / 16)   // 12500: 16 rows per block

// memn is stored in MFMA-FRAGMENT ORDER: for 16-row group g, k-chunk kc
// (32 cols), frag index f = g*8 + kc occupies bytes [f*1024, f*1024+1024):
// byte l*16+j*2 holds element (row = g*16 + (l&15), col = kc*32 + (l>>4)*8 + j).
// Staging a fragment = ONE contiguous 1KB global_load_lds (lane l -> l*16).

__device__ __forceinline__ float wred_sum(float v) {
#pragma unroll
  for (int o = 1; o < 64; o <<= 1) v += __shfl_xor(v, o, 64);
  return v;
}

// descending top-16 insert; compile-time indices only (stays in VGPRs)
__device__ __forceinline__ void topk_insert(float (&lst)[16], float v) {
  if (v <= lst[15]) return;
#pragma unroll
  for (int i = 0; i < 16; ++i) {
    bool gt = v > lst[i];
    float hi = gt ? v : lst[i];
    v = gt ? lst[i] : v;
    lst[i] = hi;
  }
}

__device__ __forceinline__ void load_lds16(const void* g, void* l) {
  __builtin_amdgcn_global_load_lds(
      (const __attribute__((address_space(1))) unsigned int*)g,
      (__attribute__((address_space(3))) unsigned int*)l, 16, 0, 0);
}

// ---------- fused: forward model (blocks 0..1023) + memcvt (blocks 1024+) ---
// fwd first so the serial MLP blocks overlap memcvt instead of tailing.
__global__ __launch_bounds__(256) void prep_kernel(
    const float* __restrict__ mem, __bf16* __restrict__ memn,
    const float* __restrict__ z_t, const float* __restrict__ action,
    const float* __restrict__ z_t1, const float* __restrict__ sigma,
    const float* __restrict__ W1, const float* __restrict__ b1,
    const float* __restrict__ g1, const float* __restrict__ be1,
    const float* __restrict__ W2, const float* __restrict__ b2,
    const float* __restrict__ g2, const float* __restrict__ be2,
    const float* __restrict__ W3, const float* __restrict__ b3,
    float* __restrict__ out, __bf16* __restrict__ z_n) {
  __shared__ float s_inp[D_N + A_N];
  __shared__ float s_h1[H1_N];
  __shared__ float s_h2[H2_N];
  __shared__ float red[8];
  __shared__ __bf16 s_rows[16 * 264];  // 16 rows x 528 B pitch (bank pad)
  const int t = threadIdx.x;
  const int w = t >> 6;
  const int l = t & 63;

  if (blockIdx.x >= B_N) {
    // ---- memcvt: 16 rows/block. Per-instruction contiguity both ways:
    // read = wave-per-row (1KB contiguous/instr, 64-lane wred_sum = row norm);
    // LDS eats the row->fragment transpose (528B pitch: 2-4-way, ~free);
    // store = one full 1KB fragment per instruction.
    const int g16 = blockIdx.x - B_N;   // 16-row group
#pragma unroll
    for (int i = 0; i < 4; ++i) {
      const int r = i * 4 + w;          // row within group, wave-uniform
      const f32x4 v =
          *(const f32x4*)(mem + ((size_t)g16 * 16 + r) * D_N + l * 4);
      float ss = v[0] * v[0] + v[1] * v[1] + v[2] * v[2] + v[3] * v[3];
      ss = wred_sum(ss);
      const float inv = 1.0f / (sqrtf(ss) + 1e-8f);
      bf16x4 p;
      p[0] = (__bf16)(v[0] * inv); p[1] = (__bf16)(v[1] * inv);
      p[2] = (__bf16)(v[2] * inv); p[3] = (__bf16)(v[3] * inv);
      *(bf16x4*)((char*)s_rows + r * 528 + l * 8) = p;
    }
    __syncthreads();
    char* dstb = (char*)memn + (size_t)g16 * 8192;  // 8 frags x 1024 B
#pragma unroll
    for (int s = 0; s < 2; ++s) {
      const int kc = w * 2 + s;         // wave-uniform fragment index
      bf16x8 chunk = *(const bf16x8*)((char*)s_rows + (l & 15) * 528 +
                                      kc * 64 + (l >> 4) * 16);
      *(bf16x8*)(dstb + kc * 1024 + l * 16) = chunk;
    }
    return;
  }

  // ---- forward model for sample b ----
  const int b = blockIdx.x;

  float zv = z_t[b * D_N + t];
  s_inp[t] = zv;
  if (t < A_N) s_inp[D_N + t] = action[b * A_N + t];

  float ss = wred_sum(zv * zv);
  if ((t & 63) == 0) red[w] = ss;
  __syncthreads();
  float tot = red[0] + red[1] + red[2] + red[3];
  float invz = 1.0f / (sqrtf(tot) + 1e-8f);
  z_n[b * D_N + t] = (__bf16)(zv * invz);

  float y1 = 0.0f;
  if (t < H1_N) {
    y1 = b1[t];
    for (int k = 0; k < D_N + A_N; ++k) y1 += s_inp[k] * W1[k * H1_N + t];
  }
  __syncthreads();
  float s1 = wred_sum(t < H1_N ? y1 : 0.0f);
  float q1 = wred_sum(t < H1_N ? y1 * y1 : 0.0f);
  if ((t & 63) == 0) { red[w] = s1; red[4 + w] = q1; }
  __syncthreads();
  float S1 = red[0] + red[1] + red[2] + red[3];
  float Q1 = red[4] + red[5] + red[6] + red[7];
  float mu1 = S1 / (float)H1_N;
  float var1 = Q1 / (float)H1_N - mu1 * mu1;
  float rs1 = rsqrtf(var1 + 1e-5f);
  if (t < H1_N) {
    float xn = (y1 - mu1) * rs1;
    s_h1[t] = fmaxf(0.0f, xn * g1[t] + be1[t]);
  }
  __syncthreads();

  float y2 = 0.0f;
  if (t < H2_N) {
    y2 = b2[t];
    for (int k = 0; k < H1_N; ++k) y2 += s_h1[k] * W2[k * H2_N + t];
  }
  __syncthreads();
  float s2 = wred_sum(t < H2_N ? y2 : 0.0f);
  float q2 = wred_sum(t < H2_N ? y2 * y2 : 0.0f);
  if ((t & 63) == 0) { red[w] = s2; red[4 + w] = q2; }
  __syncthreads();
  float S2 = red[0] + red[1] + red[2] + red[3];
  float Q2 = red[4] + red[5] + red[6] + red[7];
  float mu2 = S2 / (float)H2_N;
  float var2 = Q2 / (float)H2_N - mu2 * mu2;
  float rs2 = rsqrtf(var2 + 1e-5f);
  if (t < H2_N) {
    float xn = (y2 - mu2) * rs2;
    s_h2[t] = fmaxf(0.0f, xn * g2[t] + be2[t]);
  }
  __syncthreads();

  float zp = b3[t];
  for (int k = 0; k < H2_N; ++k) zp += s_h2[k] * W3[k * D_N + t];
  float d = zp - z_t1[b * D_N + t];
  __syncthreads();
  float pe = wred_sum(d * d);
  if ((t & 63) == 0) red[w] = pe;
  __syncthreads();
  if (t == 0) {
    float PE = (red[0] + red[1] + red[2] + red[3]) / (float)D_N;
    out[B_N + b] = PE;
    float s6 = 0.0f;
    for (int i = 0; i < A_N; ++i) s6 += sigma[b * A_N + i];
    out[2 * B_N + b] = s6 / (float)A_N;
  }
}

// ---------------- prepass: exact top-16 over 12288-row sample ---------------
// grid (S_CHUNKS, 8), 512 thr = 8 waves x 16 b-cols; fragment staging.
__global__ __launch_bounds__(512) void prepass_kernel(
    const __bf16* __restrict__ memn, const __bf16* __restrict__ z_n,
    float* __restrict__ tcand) {
  __shared__ __bf16 tile[64 * 256];  // 32 frags x 1024 B
  const int t = threadIdx.x;
  const int w = t >> 6;
  const int l = t & 63;
  const int c = l & 15;
  const int lg = l >> 4;
  const int brow = blockIdx.y * 128 + w * 16 + c;

  bf16x8 zf[8];
#pragma unroll
  for (int kc = 0; kc < 8; ++kc)
    zf[kc] = *(const bf16x8*)(z_n + brow * D_N + kc * 32 + lg * 8);

  float lst[16];
#pragma unroll
  for (int i = 0; i < 16; ++i) lst[i] = -3.0e38f;

  char* tileb = (char*)tile;
  const char* fragb = (const char*)memn;

  for (int tl = 0; tl < S_TILES; ++tl) {
    const size_t f0 = (size_t)(blockIdx.x * S_TILES + tl) * 32;
#pragma unroll
    for (int i = 0; i < 4; ++i) {
      const int f = w * 4 + i;
      load_lds16(fragb + (f0 + f) * 1024 + l * 16, tileb + f * 1024);
    }
    __syncthreads();
#pragma unroll
    for (int mf = 0; mf < 4; ++mf) {
      f32x4 acc = {0.f, 0.f, 0.f, 0.f};
#pragma unroll
      for (int kc = 0; kc < 8; ++kc) {
        bf16x8 a = *(const bf16x8*)(tileb + (mf * 8 + kc) * 1024 + l * 16);
        acc = __builtin_amdgcn_mfma_f32_16x16x32_bf16(a, zf[kc], acc, 0, 0, 0);
      }
      topk_insert(lst, acc[0]);
      topk_insert(lst, acc[1]);
      topk_insert(lst, acc[2]);
      topk_insert(lst, acc[3]);
    }
    __syncthreads();
  }

  float mg[16];
#pragma unroll
  for (int r = 0; r < 16; ++r) {
    float h = lst[0];
    float g = fmaxf(h, __shfl_xor(h, 16, 64));
    g = fmaxf(g, __shfl_xor(g, 32, 64));
    unsigned long long bal = __ballot(h == g);
    unsigned long long grp = (bal >> c) & 0x0001000100010001ULL;
    int fs = __ffsll(grp) - 1;
    if ((lg << 4) == fs) {
#pragma unroll
      for (int i = 0; i < 15; ++i) lst[i] = lst[i + 1];
      lst[15] = -3.0e38f;
    }
    mg[r] = g;
  }
  if (l < 16) {
    float* dst = tcand + ((size_t)brow * S_CHUNKS + blockIdx.x) * 16;
#pragma unroll
    for (int i = 0; i < 16; i += 4) {
      float4 o = make_float4(mg[i], mg[i + 1], mg[i + 2], mg[i + 3]);
      *(float4*)(dst + i) = o;
    }
  }
}

// -------- tau: 16th-largest of the sample candidates (+ zero cnt) -----------
__global__ __launch_bounds__(64) void tau_kernel(
    const float* __restrict__ tcand, float* __restrict__ tau,
    int* __restrict__ cnt) {
  const int b = blockIdx.x;
  const int l = threadIdx.x;
  if (l == 0) cnt[b] = 0;
  float lst[16];
#pragma unroll
  for (int i = 0; i < 16; ++i) lst[i] = -3.0e38f;
  const float* cb = tcand + (size_t)b * (S_CHUNKS * 16);
#pragma unroll
  for (int k = 0; k < (S_CHUNKS * 16) / 64; ++k) topk_insert(lst, cb[k * 64 + l]);

  float g16 = -3.0e38f;
#pragma unroll
  for (int r = 0; r < K_N; ++r) {
    float h = lst[0];
    float g = h;
#pragma unroll
    for (int o = 1; o < 64; o <<= 1) g = fmaxf(g, __shfl_xor(g, o, 64));
    unsigned long long bal = __ballot(h == g);
    int winner = __ffsll(bal) - 1;
    if (l == winner) {
#pragma unroll
      for (int i = 0; i < 15; ++i) lst[i] = lst[i + 1];
      lst[15] = -3.0e38f;
    }
    g16 = g;
  }
  if (l == 0) tau[b] = g16;
}

// ---------------- filter: contiguous-frag staging, depth-4 ring -------------
// (FROZEN from R10/R11 -- out of the top-5 there.)
__global__ __launch_bounds__(512, 4) void filter_kernel(
    const __bf16* __restrict__ memn, const __bf16* __restrict__ z_n,
    const float* __restrict__ tau, int* __restrict__ cnt,
    float* __restrict__ candv) {
  __shared__ __bf16 tile[4][32 * 256];  // 4 x 16 KB ring
  const int t = threadIdx.x;
  const int w = t >> 6;   // 0..7
  const int l = t & 63;
  const int c = l & 15;
  const int lg = l >> 4;
  const int bx = blockIdx.x;
  const int bbase = blockIdx.y * 256 + w * 32 + c;  // + s*16, s=0..1

  f32x4 zr[2][8];  // 64 VGPRs
#pragma unroll
  for (int s = 0; s < 2; ++s)
#pragma unroll
    for (int kc = 0; kc < 8; ++kc)
      zr[s][kc] = *(const f32x4*)(z_n + (size_t)(bbase + s * 16) * D_N +
                                  kc * 32 + lg * 8);

  const float tau0 = tau[bbase];
  const float tau1 = tau[bbase + 16];

  float s0a = 0.f, s0b = 0.f, s1a = 0.f, s1b = 0.f;
  int n0 = 0, n1 = 0;

  char* tileb = (char*)tile;
  const char* fragb = (const char*)memn;
#define STAGE(buf, tl_)                                                       \
  {                                                                           \
    const char* _g = fragb + ((size_t)(tl_) * 16 + w * 2) * 1024 + l * 16;    \
    char* _d = tileb + (buf) * 16384 + w * 2048;                              \
    load_lds16(_g, _d);                                                       \
    load_lds16(_g + 1024, _d + 1024);                                         \
  }

  STAGE(0, bx)
  STAGE(1, bx + F_NC)
  STAGE(2, bx + 2 * F_NC)
  STAGE(3, bx + 3 * F_NC)

  int it = 0;
  for (int tl = bx; tl < NT32; tl += F_NC, ++it) {
    asm volatile("s_waitcnt vmcnt(6)" ::: "memory");
    __builtin_amdgcn_s_barrier();
    __builtin_amdgcn_sched_barrier(0);
#pragma unroll
    for (int s = 0; s < 2; ++s)
#pragma unroll
      for (int kc = 0; kc < 8; ++kc) asm volatile("" : "+v"(zr[s][kc]));
    const char* curb = tileb + (it & 3) * 16384;
#pragma unroll
    for (int mf = 0; mf < 2; ++mf) {
      f32x4 acc0 = {0.f, 0.f, 0.f, 0.f};
      f32x4 acc1 = {0.f, 0.f, 0.f, 0.f};
#pragma unroll
      for (int kc = 0; kc < 8; ++kc) {
        bf16x8 a = *(const bf16x8*)(curb + (mf * 8 + kc) * 1024 + l * 16);
        acc0 = __builtin_amdgcn_mfma_f32_16x16x32_bf16(
            a, __builtin_bit_cast(bf16x8, zr[0][kc]), acc0, 0, 0, 0);
        acc1 = __builtin_amdgcn_mfma_f32_16x16x32_bf16(
            a, __builtin_bit_cast(bf16x8, zr[1][kc]), acc1, 0, 0, 0);
      }
      float m0 = fmaxf(fmaxf(acc0[0], acc0[1]), fmaxf(acc0[2], acc0[3]));
      if (m0 >= tau0) {
#pragma unroll
        for (int j = 0; j < 4; ++j) {
          float v = acc0[j];
          if (v >= tau0) {
            if (n0 == 0) { s0a = v; n0 = 1; }
            else if (n0 == 1) { s0b = v; n0 = 2; }
            else {
              int p = atomicAdd(&cnt[bbase], 1);
              if (p < CAP) candv[(size_t)bbase * CAP + p] = v;
            }
          }
        }
      }
      float m1 = fmaxf(fmaxf(acc1[0], acc1[1]), fmaxf(acc1[2], acc1[3]));
      if (m1 >= tau1) {
#pragma unroll
        for (int j = 0; j < 4; ++j) {
          float v = acc1[j];
          if (v >= tau1) {
            if (n1 == 0) { s1a = v; n1 = 1; }
            else if (n1 == 1) { s1b = v; n1 = 2; }
            else {
              int p = atomicAdd(&cnt[bbase + 16], 1);
              if (p < CAP) candv[(size_t)(bbase + 16) * CAP + p] = v;
            }
          }
        }
      }
    }
    asm volatile("s_waitcnt lgkmcnt(0)" ::: "memory");
    __builtin_amdgcn_s_barrier();
    int nx = tl + 4 * F_NC;
    if (nx >= NT32) nx = bx;
    STAGE(it & 3, nx)
  }
#undef STAGE

  if (n0 > 0) {
    int p = atomicAdd(&cnt[bbase], n0);
    if (p < CAP) candv[(size_t)bbase * CAP + p] = s0a;
    if (n0 == 2 && p + 1 < CAP) candv[(size_t)bbase * CAP + p + 1] = s0b;
  }
  if (n1 > 0) {
    const int bb = bbase + 16;
    int p = atomicAdd(&cnt[bb], n1);
    if (p < CAP) candv[(size_t)bb * CAP + p] = s1a;
    if (n1 == 2 && p + 1 < CAP) candv[(size_t)bb * CAP + p + 1] = s1b;
  }
}

// ---------------- final: exact top-16 of survivors + combine ----------------
__global__ __launch_bounds__(64) void final_kernel(
    const int* __restrict__ cnt, const float* __restrict__ candv,
    float* __restrict__ out) {
  const int b = blockIdx.x;
  const int l = threadIdx.x;
  const int n = min(cnt[b], CAP);
  float lst[16];
#pragma unroll
  for (int i = 0; i < 16; ++i) lst[i] = -3.0e38f;
  const float* cb = candv + (size_t)b * CAP;
  for (int k = l; k < n; k += 64) topk_insert(lst, cb[k]);

  float sum = 0.0f;
#pragma unroll
  for (int r = 0; r < K_N; ++r) {
    float h = lst[0];
    float g = h;
#pragma unroll
    for (int o = 1; o < 64; o <<= 1) g = fmaxf(g, __shfl_xor(g, o, 64));
    unsigned long long bal = __ballot(h == g);
    int winner = __ffsll(bal) - 1;
    if (l == winner) {
#pragma unroll
      for (int i = 0; i < 15; ++i) lst[i] = lst[i + 1];
      lst[15] = -3.0e38f;
    }
    sum += g;
  }
  float nov = 1.0f - sum / (float)K_N;
  nov = fminf(fmaxf(nov, 0.0f), 1.0f);
  if (l == 0) {
    float pe = out[B_N + b];
    float ep = out[2 * B_N + b];
    out[b] = pe + 0.5f * ep + 0.5f * nov;
    out[3 * B_N + b] = nov;
  }
}

extern "C" void kernel_launch(void* const* d_in, const int* in_sizes, int n_in,
                              void* d_out, int out_size, void* d_ws, size_t ws_size,
                              hipStream_t stream) {
  (void)in_sizes; (void)n_in; (void)out_size; (void)ws_size;
  const float* z_t    = (const float*)d_in[0];
  const float* action = (const float*)d_in[1];
  const float* z_t1   = (const float*)d_in[2];
  const float* sigma  = (const float*)d_in[3];
  const float* mem    = (const float*)d_in[4];
  const float* W1 = (const float*)d_in[5];
  const float* b1 = (const float*)d_in[6];
  const float* g1 = (const float*)d_in[7];
  const float* be1= (const float*)d_in[8];
  const float* W2 = (const float*)d_in[9];
  const float* b2 = (const float*)d_in[10];
  const float* g2 = (const float*)d_in[11];
  const float* be2= (const float*)d_in[12];
  const float* W3 = (const float*)d_in[13];
  const float* b3 = (const float*)d_in[14];
  float* out = (float*)d_out;

  char* ws = (char*)d_ws;
  __bf16* memn  = (__bf16*)ws;                          // 102,400,000 B (frag order)
  __bf16* z_n   = (__bf16*)(ws + 102400256);            // 524,288 B
  float*  tcand = (float*)(ws + 102924544);             // 2,097,152 B
  float*  tau   = (float*)(ws + 105021696);             // 4,096 B
  int*    cnt   = (int*)(ws + 105025792);               // 4,096 B
  float*  candv = (float*)(ws + 105029888);             // 4,194,304 B

  prep_kernel<<<B_N + MEMCVT_BLKS, 256, 0, stream>>>(
      mem, memn, z_t, action, z_t1, sigma,
      W1, b1, g1, be1, W2, b2, g2, be2, W3, b3, out, z_n);
  prepass_kernel<<<dim3(S_CHUNKS, 8), 512, 0, stream>>>(memn, z_n, tcand);
  tau_kernel<<<B_N, 64, 0, stream>>>(tcand, tau, cnt);
  filter_kernel<<<dim3(F_NC, F_BY), 512, 0, stream>>>(memn, z_n, tau, cnt, candv);
  final_kernel<<<B_N, 64, 0, stream>>>(cnt, candv, out);
}